// Round 1
// 4024.276 us; speedup vs baseline: 1.0890x; 1.0890x over previous
//
#include <hip/hip_runtime.h>

// ---------------- problem constants ----------------
#define B_RUNS 500
#define WAYS   5
#define NSUP   25
#define NQ     75
#define NN     100
#define DIM    640
#define TOPK   6
#define KHOP   4
#define NEPOCH 10

// ---------------- barrier control region ----------------
#define CTRL_BYTES 262144
#define NBK    20                 // buckets
#define BPB    25                 // blocks per bucket (500/20)
#define NROUND 1024

// per-episode doubles: Gf [10000] | Inv [10000] | (scratch slot unused now)
#define EP_DBL   30016            // unchanged layout (k2 offsets preserved)
#define GF_OFF   0
#define INV_OFF  10000

// k1 LDS: G padded to stride 101 (bank-conflict mitigation for column pass)
#define GS   101
#define GOFF (NN * GS)                       // 10100 doubles
#define DYN_LDS_DBL  (GOFF + 3232)           // + 2-team gram staging
#define DYN_LDS_BYTES (DYN_LDS_DBL * 8)      // 106656 B

// ---------------- fast wave-64 helpers ----------------
template <int CTRL>
__device__ __forceinline__ double dpp_add(double v) {
  union { double d; int i[2]; } s, r;
  s.d = v;
  r.i[0] = __builtin_amdgcn_update_dpp(0, s.i[0], CTRL, 0xF, 0xF, false);
  r.i[1] = __builtin_amdgcn_update_dpp(0, s.i[1], CTRL, 0xF, 0xF, false);
  return v + r.d;
}

template <int PAT>
__device__ __forceinline__ double swz_add(double v) {
  union { double d; int i[2]; } s, r;
  s.d = v;
  r.i[0] = __builtin_amdgcn_ds_swizzle(s.i[0], PAT);
  r.i[1] = __builtin_amdgcn_ds_swizzle(s.i[1], PAT);
  return v + r.d;
}

// full 64-lane sum: 4 DPP row-rotate adds (VALU) + xor16 swizzle + xor32 shfl,
// then broadcast lane 0 so the value is uniform across lanes.
__device__ __forceinline__ double wsum64d_fast(double v) {
  v = dpp_add<0x121>(v);     // row_ror:1
  v = dpp_add<0x122>(v);     // row_ror:2
  v = dpp_add<0x124>(v);     // row_ror:4
  v = dpp_add<0x128>(v);     // row_ror:8  -> every lane holds its 16-row sum
  v = swz_add<0x401F>(v);    // xor 16 within 32
  v += __shfl_xor(v, 32, 64);
  union { double d; unsigned u[2]; } s; s.d = v;
  s.u[0] = __builtin_amdgcn_readfirstlane(s.u[0]);
  s.u[1] = __builtin_amdgcn_readfirstlane(s.u[1]);
  return s.d;
}

// fast f64 reciprocal: hw rcp seed + 2 Newton steps (<= 1 ulp)
__device__ __forceinline__ double frcp(double x) {
#if __has_builtin(__builtin_amdgcn_rcp)
  double r = __builtin_amdgcn_rcp(x);
#else
  double r = (double)(1.0f / (float)x);
#endif
  double e = fma(-x, r, 1.0);
  r = fma(r, e, r);
  e = fma(-x, r, 1.0);
  r = fma(r, e, r);
  return r;
}

// 2-level grid barrier + global max of payload. Requires all 500 blocks co-resident.
__device__ unsigned grid_barrier_max(unsigned* ctrlu, int b, unsigned rnd, unsigned lm) {
  unsigned r = rnd < (NROUND - 1) ? rnd : (NROUND - 1);
  int bk = b % NBK;
  unsigned* barr = ctrlu + bk * NROUND + r;
  unsigned* bmax = ctrlu + (NBK + bk) * NROUND + r;
  unsigned* marr = ctrlu + 2 * NBK * NROUND + r;
  unsigned* mmax = ctrlu + 2 * NBK * NROUND + NROUND + r;
  atomicMax(bmax, lm);
  unsigned a = __hip_atomic_fetch_add(barr, 1u, __ATOMIC_ACQ_REL, __HIP_MEMORY_SCOPE_AGENT);
  if (a == (unsigned)(BPB - 1)) {
    unsigned bm = __hip_atomic_load(bmax, __ATOMIC_RELAXED, __HIP_MEMORY_SCOPE_AGENT);
    atomicMax(mmax, bm);
    __hip_atomic_fetch_add(marr, 1u, __ATOMIC_ACQ_REL, __HIP_MEMORY_SCOPE_AGENT);
  }
  long sp = 0;
  while (__hip_atomic_load(marr, __ATOMIC_ACQUIRE, __HIP_MEMORY_SCOPE_AGENT) < (unsigned)NBK) {
    __builtin_amdgcn_s_sleep(2);
    if (++sp > 20000000L) break;   // safety: terminate, don't hang
  }
  return __hip_atomic_load(mmax, __ATOMIC_RELAXED, __HIP_MEMORY_SCOPE_AGENT);
}

// =====================================================================
// Kernel 1 (gram-space): initial fp64 gram, then per hop: top-6 ->
// sparse L -> congruence G <- L(LGL^T)L^T done ENTIRELY IN-PLACE IN LDS
// (column-pass L*G, row-pass *L^T) -- no global R scratch. Hop 3: Gf,
// dense L^2, W chain, M = I-0.7W, Gauss-Jordan inverse -> Inv.
// =====================================================================
__global__ __launch_bounds__(512) void k1_lds(const float* __restrict__ xs,
                                              const float* __restrict__ xq,
                                              char* __restrict__ wsb) {
  extern __shared__ double dynb[];
  double* G  = dynb;            // 100 x 101 (padded stride)
  double* ST = dynb + GOFF;     // 2 teams x 1616 gram staging

  const int b = blockIdx.x;
  double* ep  = (double*)(wsb + CTRL_BYTES) + (size_t)b * EP_DBL;
  double* Gf  = ep + GF_OFF;
  double* Inv = ep + INV_OFF;

  __shared__ double nsh[NN], Dsh[NN], rowk[NN], colk[NN];
  __shared__ double wS[NN][7];
  __shared__ int    idxS[NN][7];
  __shared__ int    cntS[NN];

  const int t  = threadIdx.x;
  const int tm = t >> 8;              // team 0/1
  const int tt = t & 255;
  const int tx = tt & 15, ty = tt >> 4;
  double* STt = ST + tm * 1616;

  int ia[7], ja[7];
  #pragma unroll
  for (int a = 0; a < 7; ++a) { int v = ty + 16 * a; ia[a] = v < NN ? v : NN - 1; }
  #pragma unroll
  for (int a = 0; a < 7; ++a) { int v = tx + 16 * a; ja[a] = v < NN ? v : NN - 1; }

  // ---- initial gram G0 = F F^T from fp32 inputs (2-team split-K, b128 pairs) ----
  {
    double acc[7][7];
    #pragma unroll
    for (int a = 0; a < 7; ++a)
      #pragma unroll
      for (int c = 0; c < 7; ++c) acc[a][c] = 0.0;
    const float* xsb = xs + (size_t)b * NSUP * DIM;
    const float* xqb = xq + (size_t)b * NQ * DIM;
    for (int chunk = 0; chunk < 20; ++chunk) {
      int k0 = (chunk * 2 + tm) * 16;
      for (int e = tt; e < NN * 16; e += 256) {
        int r = e >> 4, km = e & 15;
        int k = k0 + km;
        float v = (r < NSUP) ? xsb[r * DIM + k] : xqb[(r - NSUP) * DIM + k];
        STt[(km >> 1) * 202 + 2 * r + (km & 1)] = (double)v;
      }
      __syncthreads();
      #pragma unroll 2
      for (int m = 0; m < 8; ++m) {
        double2 rv[7], cv[7];
        #pragma unroll
        for (int a = 0; a < 7; ++a) rv[a] = *(const double2*)(STt + m * 202 + 2 * ia[a]);
        #pragma unroll
        for (int c = 0; c < 7; ++c) cv[c] = *(const double2*)(STt + m * 202 + 2 * ja[c]);
        #pragma unroll
        for (int a = 0; a < 7; ++a)
          #pragma unroll
          for (int c = 0; c < 7; ++c) {
            acc[a][c] = fma(rv[a].x, cv[c].x, acc[a][c]);
            acc[a][c] = fma(rv[a].y, cv[c].y, acc[a][c]);
          }
      }
      __syncthreads();
    }
    if (tm == 1) {
      #pragma unroll
      for (int a = 0; a < 7; ++a)
        #pragma unroll
        for (int c = 0; c < 7; ++c) {
          int i = ty + 16 * a, j = tx + 16 * c;
          if (i < NN && j < NN) G[i * GS + j] = acc[a][c];
        }
    }
    __syncthreads();
    if (tm == 0) {
      #pragma unroll
      for (int a = 0; a < 7; ++a)
        #pragma unroll
        for (int c = 0; c < 7; ++c) {
          int i = ty + 16 * a, j = tx + 16 * c;
          if (i < NN && j < NN) G[i * GS + j] = acc[a][c] + G[i * GS + j];
        }
    }
    __syncthreads();
  }

  for (int hop = 0; hop < KHOP; ++hop) {
    if (t < NN) nsh[t] = G[t * GS + t];
    __syncthreads();
    // ---- top-6 per row by clamped distance (ascending; ties -> lowest index) ----
    int kj[TOPK]; double ke[TOPK];
    if (t < NN) {
      unsigned long long m0 = 0ull, m1 = 0ull;
      const double nt = nsh[t];
      for (int s = 0; s < TOPK; ++s) {
        double best = 1e300; int bj = 0;
        for (int j = 0; j < NN; ++j) {
          unsigned long long bit = (j < 64) ? ((m0 >> j) & 1ull) : ((m1 >> (j - 64)) & 1ull);
          if (bit) continue;
          double d = (nt + nsh[j]) - 2.0 * G[t * GS + j];
          d = d > 0.0 ? d : 0.0;
          if (d < best) { best = d; bj = j; }     // strict <: lowest index wins ties
        }
        if (bj < 64) m0 |= 1ull << bj; else m1 |= 1ull << (bj - 64);
      }
      // kept entries ascending (lowest set bit first); exp weights; rowsum
      double s = 0.0;
      unsigned long long mm0 = m0, mm1 = m1;
      #pragma unroll
      for (int sidx = 0; sidx < TOPK; ++sidx) {
        int j;
        if (mm0) { j = __ffsll((long long)mm0) - 1; mm0 &= mm0 - 1; }
        else     { j = 64 + __ffsll((long long)mm1) - 1; mm1 &= mm1 - 1; }
        double d = (nt + nsh[j]) - 2.0 * G[t * GS + j];
        d = d > 0.0 ? d : 0.0;
        double e = exp(-10.0 * d);
        kj[sidx] = j; ke[sidx] = e;
        s += e;
      }
      Dsh[t] = 1.0 / sqrt(s);
    }
    __syncthreads();
    // ---- build sparse L row: ascending index, self 0.5 folded/inserted ----
    if (t < NN) {
      int cnt = 0; bool sd = false;
      double dt = Dsh[t];
      #pragma unroll
      for (int sidx = 0; sidx < TOPK; ++sidx) {
        int j = kj[sidx];
        double lw = 0.5 * ((Dsh[j] * ke[sidx]) * dt);
        if (j == t) { lw = 0.5 + lw; sd = true; }
        else if (!sd && j > t) { idxS[t][cnt] = t; wS[t][cnt] = 0.5; ++cnt; sd = true; }
        idxS[t][cnt] = j; wS[t][cnt] = lw; ++cnt;
      }
      if (!sd) { idxS[t][cnt] = t; wS[t][cnt] = 0.5; ++cnt; }
      cntS[t] = cnt;
    }
    __syncthreads();

    // ---- congruence: G <- L (L G L^T) L^T, fully in-place in LDS ----
    // Lane ln owns rows/cols {ln, ln+64}; preload their sparse L rows
    // (zero-padded to 7 so inner loops are branch-free & fully unrolled).
    {
      const int wv8 = t >> 6, ln = t & 63;
      const int i2 = ln + 64;
      const bool h2 = (i2 < NN);
      const int r1 = h2 ? i2 : 0;
      double lw0[7], lw1[7]; int li0[7], li1[7];
      {
        int c0 = cntS[ln];
        int c1 = h2 ? cntS[r1] : 0;
        #pragma unroll
        for (int s2 = 0; s2 < 7; ++s2) {
          lw0[s2] = (s2 < c0) ? wS[ln][s2] : 0.0;
          li0[s2] = (s2 < c0) ? idxS[ln][s2] : 0;
          lw1[s2] = (s2 < c1) ? wS[r1][s2] : 0.0;
          li1[s2] = (s2 < c1) ? idxS[r1][s2] : 0;
        }
      }
      #pragma unroll 1
      for (int pair = 0; pair < 2; ++pair) {
        // G <- L * G : per COLUMN (one wave per column), in place.
        // Reads/writes touch only column c; within a wave all reads are
        // drained (lgkmcnt 0) before the overwriting writes issue.
        for (int c = wv8; c < NN; c += 8) {
          double o0 = 0.0, o1 = 0.0;
          #pragma unroll
          for (int s2 = 0; s2 < 7; ++s2) o0 = fma(lw0[s2], G[li0[s2] * GS + c], o0);
          #pragma unroll
          for (int s2 = 0; s2 < 7; ++s2) o1 = fma(lw1[s2], G[li1[s2] * GS + c], o1);
          asm volatile("s_waitcnt lgkmcnt(0)" ::: "memory");
          G[ln * GS + c] = o0;
          if (h2) G[i2 * GS + c] = o1;
        }
        __syncthreads();
        // G <- G * L^T : per ROW (one wave per row), in place.
        for (int r = wv8; r < NN; r += 8) {
          double o0 = 0.0, o1 = 0.0;
          #pragma unroll
          for (int s2 = 0; s2 < 7; ++s2) o0 = fma(lw0[s2], G[r * GS + li0[s2]], o0);
          #pragma unroll
          for (int s2 = 0; s2 < 7; ++s2) o1 = fma(lw1[s2], G[r * GS + li1[s2]], o1);
          asm volatile("s_waitcnt lgkmcnt(0)" ::: "memory");
          G[r * GS + ln] = o0;
          if (h2) G[r * GS + i2] = o1;
        }
        __syncthreads();
      }
    }

    if (hop == KHOP - 1) {
      // final gram out (compact stride 100)
      for (int e = t; e < NN * NN; e += 512) Gf[e] = G[(e / NN) * GS + (e % NN)];
      __syncthreads();
      // ---- dense L^2 into G (sparse scatter, ascending k order) ----
      if (t < NN) {
        for (int j = 0; j < NN; ++j) G[t * GS + j] = 0.0;
        int cnt = cntS[t];
        for (int s2 = 0; s2 < cnt; ++s2) {
          double w1 = wS[t][s2]; int k = idxS[t][s2];
          int c2 = cntS[k];
          for (int t2 = 0; t2 < c2; ++t2)
            G[t * GS + idxS[k][t2]] += w1 * wS[k][t2];
        }
      }
      __syncthreads();
      // ---- W = build_graph(build_graph(L^2)) ----
      for (int rep = 0; rep < 2; ++rep) {
        if (t < NN) G[t * GS + t] = 0.0;
        __syncthreads();
        if (t < NN) {
          double s = 0.0;
          for (int j = 0; j < NN; ++j) s += G[t * GS + j];
          Dsh[t] = 1.0 / sqrt(s);
        }
        __syncthreads();
        for (int e = t; e < NN * NN; e += 512) {
          int i = e / NN, j = e % NN;
          G[i * GS + j] = (Dsh[j] * G[i * GS + j]) * Dsh[i];
        }
        __syncthreads();
      }
      // M = I - 0.7*W
      for (int e = t; e < NN * NN; e += 512) {
        int i = e / NN, j = e % NN;
        G[i * GS + j] = ((i == j) ? 1.0 : 0.0) - 0.7 * G[i * GS + j];
      }
      __syncthreads();
      // ---- Gauss-Jordan sweep inverse in LDS ----
      for (int k = 0; k < NN; ++k) {
        if (t < NN) { rowk[t] = G[k * GS + t]; colk[t] = G[t * GS + k]; }
        __syncthreads();
        double pinv = 1.0 / rowk[k];
        for (int e = t; e < NN * NN; e += 512) {
          int i = e / NN, j = e % NN;
          double v;
          if (i == k)      v = (j == k) ? pinv : rowk[j] * pinv;
          else if (j == k) v = -(colk[i] * pinv);
          else             v = G[i * GS + j] - colk[i] * (rowk[j] * pinv);
          G[i * GS + j] = v;
        }
        __syncthreads();
      }
      for (int e = t; e < NN * NN; e += 512) Inv[e] = G[(e / NN) * GS + (e % NN)];
    }
  }
}

// =====================================================================
// Kernel 2: epochs + lockstep sinkhorn. Changes vs prior round:
//  - wmax64d convergence reduction -> __any (one v_cmp, no bpermute chain)
//  - wsum64d -> DPP-rotate + swizzle fast path (2 LDS-latency stages vs 6)
//  - IEEE f64 divides on the iteration critical path -> rcp + 2 Newton
// =====================================================================
__global__ __launch_bounds__(256, 2) void k2_epochs(const int* __restrict__ ys,
                                                    const int* __restrict__ yq,
                                                    char* __restrict__ wsb,
                                                    float* __restrict__ out) {
  const int b = blockIdx.x;
  const double* G   = (const double*)(wsb + CTRL_BYTES) + (size_t)b * EP_DBL;
  const double* Inv = G + INV_OFF;
  unsigned* ctrlu = (unsigned*)wsb;

  __shared__ double Z[NN * WAYS];
  __shared__ double gvF[WAYS * NN];
  __shared__ double pbuf[4][WAYS * NN];
  __shared__ double betaS[WAYS][NN];
  __shared__ double nrmS[NN];
  __shared__ double csv[WAYS], pnS[WAYS];
  __shared__ int ysS[NSUP];
  __shared__ unsigned Tsh;
  __shared__ int redi;

  const int t  = threadIdx.x;
  const int wv = t >> 6, ln = t & 63;
  unsigned rnd = 0;

  if (t < NSUP) ysS[t] = ys[b * NSUP + t];
  if (t < NN)   nrmS[t] = G[t * NN + t];
  for (int e = t; e < WAYS * NN; e += 256) {
    int w = e / NN, n = e % NN;
    betaS[w][n] = (n >= w * 5 && n < w * 5 + 5) ? 0.2 : 0.0;
  }
  __syncthreads();

  auto sinkhorn = [&](int base, int n, double cval, bool clamp) {
    const bool own = (wv == 0);
    const int r0 = ln, r1 = ln + 64;
    const bool h1 = (r1 < n);
    double p0[WAYS], p1[WAYS];
    double up0 = 0.0, up1 = 0.0, u0 = 0.0, u1 = 0.0;
    int aflag = 0;
    int m = 0; int ysq = -1;
    if (own) {
      #pragma unroll
      for (int w = 0; w < WAYS; ++w) {
        p0[w] = Z[(base + r0) * WAYS + w];
        p1[w] = h1 ? Z[(base + r1) * WAYS + w] : 0.0;
      }
      if (clamp && r0 < NSUP) ysq = ysS[r0];
      u0 = p0[0] + p0[1] + p0[2] + p0[3] + p0[4];
      if (h1) u1 = p1[0] + p1[1] + p1[2] + p1[3] + p1[4];
      double dl = fabs(up0 - u0);
      if (h1) dl = fmax(dl, fabs(up1 - u1));
      aflag = __any(dl > 1e-3);
    }
    unsigned target = 0;
    for (;;) {
      if (own) {
        while (m < 1000 && ((unsigned)m < target || aflag)) {
          double i0 = frcp(u0);
          #pragma unroll
          for (int w = 0; w < WAYS; ++w) p0[w] *= i0;
          up0 = u0;
          if (h1) {
            double i1 = frcp(u1);
            #pragma unroll
            for (int w = 0; w < WAYS; ++w) p1[w] *= i1;
            up1 = u1;
          }
          #pragma unroll
          for (int w = 0; w < WAYS; ++w) {
            double s = wsum64d_fast(p0[w] + (h1 ? p1[w] : 0.0));
            double f = cval * frcp(s);
            p0[w] *= f;
            if (h1) p1[w] *= f;
          }
          if (clamp && r0 < NSUP) {
            #pragma unroll
            for (int w = 0; w < WAYS; ++w) p0[w] = (ysq == w) ? 1.0 : 0.0;
          }
          ++m;
          u0 = p0[0] + p0[1] + p0[2] + p0[3] + p0[4];
          if (h1) u1 = p1[0] + p1[1] + p1[2] + p1[3] + p1[4];
          double dl = fabs(up0 - u0);
          if (h1) dl = fmax(dl, fabs(up1 - u1));
          aflag = __any(dl > 1e-3);
        }
      }
      __syncthreads();
      if (t == 0) Tsh = grid_barrier_max(ctrlu, b, rnd, (unsigned)m);
      __syncthreads();
      ++rnd;
      unsigned T = Tsh;
      if (T == target) break;
      target = T;
    }
    if (own) {
      #pragma unroll
      for (int w = 0; w < WAYS; ++w) {
        Z[(base + r0) * WAYS + w] = p0[w];
        if (h1) Z[(base + r1) * WAYS + w] = p1[w];
      }
    }
    __syncthreads();
  };

  for (int epi = 0; epi <= NEPOCH; ++epi) {
    // gv[w][r] = sum_k G[r][k]*beta[w][k]  (k split over waves)
    {
      double a0[WAYS], a1[WAYS];
      #pragma unroll
      for (int w = 0; w < WAYS; ++w) { a0[w] = 0.0; a1[w] = 0.0; }
      int k0 = wv * 25;
      for (int kk = 0; kk < 25; ++kk) {
        int k = k0 + kk;
        double g0 = G[(size_t)k * NN + ln];
        double g1 = (ln < NN - 64) ? G[(size_t)k * NN + 64 + ln] : 0.0;
        #pragma unroll
        for (int w = 0; w < WAYS; ++w) {
          double bw = betaS[w][k];
          a0[w] = fma(g0, bw, a0[w]);
          a1[w] = fma(g1, bw, a1[w]);
        }
      }
      #pragma unroll
      for (int w = 0; w < WAYS; ++w) {
        pbuf[wv][w * NN + ln] = a0[w];
        if (ln < NN - 64) pbuf[wv][w * NN + 64 + ln] = a1[w];
      }
    }
    __syncthreads();
    for (int e = t; e < WAYS * NN; e += 256)
      gvF[e] = ((pbuf[0][e] + pbuf[1][e]) + pbuf[2][e]) + pbuf[3][e];
    __syncthreads();
    if (t < WAYS) {
      double s = 0.0;
      for (int n = 0; n < NN; ++n) s = fma(betaS[t][n], gvF[t * NN + n], s);
      pnS[t] = s;
    }
    __syncthreads();
    for (int e = t; e < NQ * WAYS; e += 256) {
      int r = NSUP + e / WAYS, w = e % WAYS;
      double d = (nrmS[r] + pnS[w]) - 2.0 * gvF[w * NN + r];
      Z[r * WAYS + w] = exp(-10.0 * (d > 0.0 ? d : 0.0));
    }
    __syncthreads();
    sinkhorn(NSUP, NQ, 15.0, false);

    if (epi == NEPOCH) {
      if (t == 0) redi = 0;
      __syncthreads();
      if (t < NQ) {
        int row = NSUP + t;
        double bv = Z[row * WAYS + 0]; int am = 0;
        #pragma unroll
        for (int w = 1; w < WAYS; ++w) {
          double v = Z[row * WAYS + w];
          if (v > bv) { bv = v; am = w; }
        }
        if (am == yq[b * NQ + t]) atomicAdd(&redi, 1);
      }
      __syncthreads();
      if (t == 0) out[b] = (float)((double)redi / 75.0);
    } else {
      if (t < NSUP) {
        #pragma unroll
        for (int w = 0; w < WAYS; ++w) Z[t * WAYS + w] = (ysS[t] == w) ? 1.0 : 0.0;
      }
      __syncthreads();
      for (int r = wv; r < NN; r += 4) {
        double a0 = 0, a1 = 0, a2 = 0, a3 = 0, a4 = 0;
        for (int k = ln; k < NN; k += 64) {
          double iv = Inv[(size_t)r * NN + k];
          a0 = fma(iv, Z[k * WAYS + 0], a0);
          a1 = fma(iv, Z[k * WAYS + 1], a1);
          a2 = fma(iv, Z[k * WAYS + 2], a2);
          a3 = fma(iv, Z[k * WAYS + 3], a3);
          a4 = fma(iv, Z[k * WAYS + 4], a4);
        }
        a0 = wsum64d_fast(a0); a1 = wsum64d_fast(a1); a2 = wsum64d_fast(a2);
        a3 = wsum64d_fast(a3); a4 = wsum64d_fast(a4);
        if (ln == 0) {
          pbuf[0][r * WAYS + 0] = a0; pbuf[0][r * WAYS + 1] = a1;
          pbuf[0][r * WAYS + 2] = a2; pbuf[0][r * WAYS + 3] = a3;
          pbuf[0][r * WAYS + 4] = a4;
        }
      }
      __syncthreads();
      for (int e = t; e < NN * WAYS; e += 256) Z[e] = pbuf[0][e];
      __syncthreads();
      sinkhorn(0, NN, 20.0, true);
      if (t < WAYS) {
        double s = 0.0;
        for (int r = 0; r < NN; ++r) s += Z[r * WAYS + t];
        csv[t] = s;
      }
      __syncthreads();
      for (int e = t; e < NN * WAYS; e += 256) {
        int n = e / WAYS, w = e % WAYS;
        double nb = Z[n * WAYS + w] / csv[w];
        betaS[w][n] = 0.4 * betaS[w][n] + 0.6 * nb;
      }
      __syncthreads();
    }
  }
}

extern "C" void kernel_launch(void* const* d_in, const int* in_sizes, int n_in,
                              void* d_out, int out_size, void* d_ws, size_t ws_size,
                              hipStream_t stream) {
  const float* xs = (const float*)d_in[0];
  const float* xq = (const float*)d_in[1];
  const int*   ys = (const int*)d_in[2];
  const int*   yq = (const int*)d_in[3];
  float* out = (float*)d_out;
  char* ws   = (char*)d_ws;

  hipMemsetAsync(d_ws, 0, CTRL_BYTES, stream);

  (void)hipFuncSetAttribute((const void*)k1_lds,
                            hipFuncAttributeMaxDynamicSharedMemorySize,
                            DYN_LDS_BYTES);
  hipLaunchKernelGGL(k1_lds, dim3(B_RUNS), dim3(512), DYN_LDS_BYTES, stream, xs, xq, ws);
  hipLaunchKernelGGL(k2_epochs, dim3(B_RUNS), dim3(256), 0, stream, ys, yq, ws, out);
}

// Round 2
// 3097.617 us; speedup vs baseline: 1.4148x; 1.2992x over previous
//
#include <hip/hip_runtime.h>

// ---------------- problem constants ----------------
#define B_RUNS 500
#define WAYS   5
#define NSUP   25
#define NQ     75
#define NN     100
#define DIM    640
#define TOPK   6
#define KHOP   4
#define NEPOCH 10

// ---------------- barrier control region ----------------
#define CTRL_BYTES 262144
#define NBK    20                 // buckets
#define BPB    25                 // blocks per bucket (500/20)
#define NROUND 1024
#define READYB 0x80000000u

// ctrl word layout (all < 65536 words = 256 KB):
//   barr [20][1024] @ 0          arrival counters (25 writers each)
//   bmax [20][1024] @ 20480      per-bucket max (25 atomicMax each)
//   marr [1024]     @ 40960      bucket-done counter (20 writers, 20 leader spinners)
//   mmax [1024]     @ 40960+1024 global max (20 atomicMax, leaders read)
//   bflag[20][1024] @ 43008      per-bucket release flag|value (1 writer, <=24 spinners)

// per-episode doubles: Gf [10000] | Inv [10000] | (scratch slot unused now)
#define EP_DBL   30016
#define GF_OFF   0
#define INV_OFF  10000

// k1 LDS: G padded to stride 101 (bank-conflict mitigation for column pass)
#define GS   101
#define GOFF (NN * GS)                       // 10100 doubles
#define DYN_LDS_DBL  (GOFF + 3232)           // + 2-team gram staging
#define DYN_LDS_BYTES (DYN_LDS_DBL * 8)      // 106656 B

// ---------------- fast wave-64 helpers ----------------
template <int CTRL>
__device__ __forceinline__ double dpp_add(double v) {
  union { double d; int i[2]; } s, r;
  s.d = v;
  r.i[0] = __builtin_amdgcn_update_dpp(0, s.i[0], CTRL, 0xF, 0xF, false);
  r.i[1] = __builtin_amdgcn_update_dpp(0, s.i[1], CTRL, 0xF, 0xF, false);
  return v + r.d;
}

template <int PAT>
__device__ __forceinline__ double swz_add(double v) {
  union { double d; int i[2]; } s, r;
  s.d = v;
  r.i[0] = __builtin_amdgcn_ds_swizzle(s.i[0], PAT);
  r.i[1] = __builtin_amdgcn_ds_swizzle(s.i[1], PAT);
  return v + r.d;
}

// full 64-lane sum: 4 DPP row-rotate adds (VALU) + xor16 swizzle + xor32 shfl,
// then broadcast lane 0 so the value is uniform across lanes.
__device__ __forceinline__ double wsum64d_fast(double v) {
  v = dpp_add<0x121>(v);     // row_ror:1
  v = dpp_add<0x122>(v);     // row_ror:2
  v = dpp_add<0x124>(v);     // row_ror:4
  v = dpp_add<0x128>(v);     // row_ror:8  -> every lane holds its 16-row sum
  v = swz_add<0x401F>(v);    // xor 16 within 32
  v += __shfl_xor(v, 32, 64);
  union { double d; unsigned u[2]; } s; s.d = v;
  s.u[0] = __builtin_amdgcn_readfirstlane(s.u[0]);
  s.u[1] = __builtin_amdgcn_readfirstlane(s.u[1]);
  return s.d;
}

// fast f64 reciprocal: hw rcp seed + 2 Newton steps (<= 1 ulp)
__device__ __forceinline__ double frcp(double x) {
#if __has_builtin(__builtin_amdgcn_rcp)
  double r = __builtin_amdgcn_rcp(x);
#else
  double r = (double)(1.0f / (float)x);
#endif
  double e = fma(-x, r, 1.0);
  r = fma(r, e, r);
  e = fma(-x, r, 1.0);
  r = fma(r, e, r);
  return r;
}

// 2-level grid barrier + global max of payload, hierarchical release.
// Only 20 leaders spin on the global line; everyone else spins RELAXED on a
// per-bucket flag (single writer, <=24 readers). One acquire fence at exit.
__device__ unsigned grid_barrier_max(unsigned* ctrlu, int b, unsigned rnd, unsigned lm) {
  unsigned r = rnd < (NROUND - 1) ? rnd : (NROUND - 1);
  const int bk = b % NBK;
  unsigned* barr  = ctrlu + bk * NROUND + r;
  unsigned* bmax  = ctrlu + (NBK + bk) * NROUND + r;
  unsigned* marr  = ctrlu + 2 * NBK * NROUND + r;
  unsigned* mmax  = ctrlu + 2 * NBK * NROUND + NROUND + r;
  unsigned* bflag = ctrlu + (2 * NBK + 2) * NROUND + bk * NROUND + r;

  __hip_atomic_fetch_max(bmax, lm, __ATOMIC_RELAXED, __HIP_MEMORY_SCOPE_AGENT);
  unsigned a = __hip_atomic_fetch_add(barr, 1u, __ATOMIC_ACQ_REL, __HIP_MEMORY_SCOPE_AGENT);
  long sp = 0;
  if (a == (unsigned)(BPB - 1)) {
    // last arriver in bucket = leader: post bucket result, spin on global line
    unsigned bm = __hip_atomic_load(bmax, __ATOMIC_RELAXED, __HIP_MEMORY_SCOPE_AGENT);
    __hip_atomic_fetch_max(mmax, bm, __ATOMIC_RELAXED, __HIP_MEMORY_SCOPE_AGENT);
    __hip_atomic_fetch_add(marr, 1u, __ATOMIC_ACQ_REL, __HIP_MEMORY_SCOPE_AGENT);
    while (__hip_atomic_load(marr, __ATOMIC_RELAXED, __HIP_MEMORY_SCOPE_AGENT) < (unsigned)NBK) {
      __builtin_amdgcn_s_sleep(1);
      if (++sp > 50000000L) break;   // safety: terminate, don't hang
    }
    __builtin_amdgcn_fence(__ATOMIC_ACQUIRE, "agent");
    unsigned g = __hip_atomic_load(mmax, __ATOMIC_RELAXED, __HIP_MEMORY_SCOPE_AGENT);
    __hip_atomic_store(bflag, g | READYB, __ATOMIC_RELEASE, __HIP_MEMORY_SCOPE_AGENT);
    return g;
  } else {
    unsigned f;
    while (!((f = __hip_atomic_load(bflag, __ATOMIC_RELAXED, __HIP_MEMORY_SCOPE_AGENT)) & READYB)) {
      __builtin_amdgcn_s_sleep(1);
      if (++sp > 50000000L) break;   // safety: terminate, don't hang
    }
    __builtin_amdgcn_fence(__ATOMIC_ACQUIRE, "agent");
    return f & ~READYB;
  }
}

// =====================================================================
// Kernel 1 (gram-space): initial fp64 gram, then per hop: top-6 ->
// sparse L -> congruence G <- L(LGL^T)L^T done ENTIRELY IN-PLACE IN LDS
// (column-pass L*G, row-pass *L^T) -- no global R scratch. Hop 3: Gf,
// dense L^2, W chain, M = I-0.7W, Gauss-Jordan inverse -> Inv.
// =====================================================================
__global__ __launch_bounds__(512) void k1_lds(const float* __restrict__ xs,
                                              const float* __restrict__ xq,
                                              char* __restrict__ wsb) {
  extern __shared__ double dynb[];
  double* G  = dynb;            // 100 x 101 (padded stride)
  double* ST = dynb + GOFF;     // 2 teams x 1616 gram staging

  const int b = blockIdx.x;
  double* ep  = (double*)(wsb + CTRL_BYTES) + (size_t)b * EP_DBL;
  double* Gf  = ep + GF_OFF;
  double* Inv = ep + INV_OFF;

  __shared__ double nsh[NN], Dsh[NN], rowk[NN], colk[NN];
  __shared__ double wS[NN][7];
  __shared__ int    idxS[NN][7];
  __shared__ int    cntS[NN];

  const int t  = threadIdx.x;
  const int tm = t >> 8;              // team 0/1
  const int tt = t & 255;
  const int tx = tt & 15, ty = tt >> 4;
  double* STt = ST + tm * 1616;

  int ia[7], ja[7];
  #pragma unroll
  for (int a = 0; a < 7; ++a) { int v = ty + 16 * a; ia[a] = v < NN ? v : NN - 1; }
  #pragma unroll
  for (int a = 0; a < 7; ++a) { int v = tx + 16 * a; ja[a] = v < NN ? v : NN - 1; }

  // ---- initial gram G0 = F F^T from fp32 inputs (2-team split-K, b128 pairs) ----
  {
    double acc[7][7];
    #pragma unroll
    for (int a = 0; a < 7; ++a)
      #pragma unroll
      for (int c = 0; c < 7; ++c) acc[a][c] = 0.0;
    const float* xsb = xs + (size_t)b * NSUP * DIM;
    const float* xqb = xq + (size_t)b * NQ * DIM;
    for (int chunk = 0; chunk < 20; ++chunk) {
      int k0 = (chunk * 2 + tm) * 16;
      for (int e = tt; e < NN * 16; e += 256) {
        int r = e >> 4, km = e & 15;
        int k = k0 + km;
        float v = (r < NSUP) ? xsb[r * DIM + k] : xqb[(r - NSUP) * DIM + k];
        STt[(km >> 1) * 202 + 2 * r + (km & 1)] = (double)v;
      }
      __syncthreads();
      #pragma unroll 2
      for (int m = 0; m < 8; ++m) {
        double2 rv[7], cv[7];
        #pragma unroll
        for (int a = 0; a < 7; ++a) rv[a] = *(const double2*)(STt + m * 202 + 2 * ia[a]);
        #pragma unroll
        for (int c = 0; c < 7; ++c) cv[c] = *(const double2*)(STt + m * 202 + 2 * ja[c]);
        #pragma unroll
        for (int a = 0; a < 7; ++a)
          #pragma unroll
          for (int c = 0; c < 7; ++c) {
            acc[a][c] = fma(rv[a].x, cv[c].x, acc[a][c]);
            acc[a][c] = fma(rv[a].y, cv[c].y, acc[a][c]);
          }
      }
      __syncthreads();
    }
    if (tm == 1) {
      #pragma unroll
      for (int a = 0; a < 7; ++a)
        #pragma unroll
        for (int c = 0; c < 7; ++c) {
          int i = ty + 16 * a, j = tx + 16 * c;
          if (i < NN && j < NN) G[i * GS + j] = acc[a][c];
        }
    }
    __syncthreads();
    if (tm == 0) {
      #pragma unroll
      for (int a = 0; a < 7; ++a)
        #pragma unroll
        for (int c = 0; c < 7; ++c) {
          int i = ty + 16 * a, j = tx + 16 * c;
          if (i < NN && j < NN) G[i * GS + j] = acc[a][c] + G[i * GS + j];
        }
    }
    __syncthreads();
  }

  for (int hop = 0; hop < KHOP; ++hop) {
    if (t < NN) nsh[t] = G[t * GS + t];
    __syncthreads();
    // ---- top-6 per row by clamped distance (ascending; ties -> lowest index) ----
    int kj[TOPK]; double ke[TOPK];
    if (t < NN) {
      unsigned long long m0 = 0ull, m1 = 0ull;
      const double nt = nsh[t];
      for (int s = 0; s < TOPK; ++s) {
        double best = 1e300; int bj = 0;
        for (int j = 0; j < NN; ++j) {
          unsigned long long bit = (j < 64) ? ((m0 >> j) & 1ull) : ((m1 >> (j - 64)) & 1ull);
          if (bit) continue;
          double d = (nt + nsh[j]) - 2.0 * G[t * GS + j];
          d = d > 0.0 ? d : 0.0;
          if (d < best) { best = d; bj = j; }     // strict <: lowest index wins ties
        }
        if (bj < 64) m0 |= 1ull << bj; else m1 |= 1ull << (bj - 64);
      }
      // kept entries ascending (lowest set bit first); exp weights; rowsum
      double s = 0.0;
      unsigned long long mm0 = m0, mm1 = m1;
      #pragma unroll
      for (int sidx = 0; sidx < TOPK; ++sidx) {
        int j;
        if (mm0) { j = __ffsll((long long)mm0) - 1; mm0 &= mm0 - 1; }
        else     { j = 64 + __ffsll((long long)mm1) - 1; mm1 &= mm1 - 1; }
        double d = (nt + nsh[j]) - 2.0 * G[t * GS + j];
        d = d > 0.0 ? d : 0.0;
        double e = exp(-10.0 * d);
        kj[sidx] = j; ke[sidx] = e;
        s += e;
      }
      Dsh[t] = 1.0 / sqrt(s);
    }
    __syncthreads();
    // ---- build sparse L row: ascending index, self 0.5 folded/inserted ----
    if (t < NN) {
      int cnt = 0; bool sd = false;
      double dt = Dsh[t];
      #pragma unroll
      for (int sidx = 0; sidx < TOPK; ++sidx) {
        int j = kj[sidx];
        double lw = 0.5 * ((Dsh[j] * ke[sidx]) * dt);
        if (j == t) { lw = 0.5 + lw; sd = true; }
        else if (!sd && j > t) { idxS[t][cnt] = t; wS[t][cnt] = 0.5; ++cnt; sd = true; }
        idxS[t][cnt] = j; wS[t][cnt] = lw; ++cnt;
      }
      if (!sd) { idxS[t][cnt] = t; wS[t][cnt] = 0.5; ++cnt; }
      cntS[t] = cnt;
    }
    __syncthreads();

    // ---- congruence: G <- L (L G L^T) L^T, fully in-place in LDS ----
    {
      const int wv8 = t >> 6, ln = t & 63;
      const int i2 = ln + 64;
      const bool h2 = (i2 < NN);
      const int r1 = h2 ? i2 : 0;
      double lw0[7], lw1[7]; int li0[7], li1[7];
      {
        int c0 = cntS[ln];
        int c1 = h2 ? cntS[r1] : 0;
        #pragma unroll
        for (int s2 = 0; s2 < 7; ++s2) {
          lw0[s2] = (s2 < c0) ? wS[ln][s2] : 0.0;
          li0[s2] = (s2 < c0) ? idxS[ln][s2] : 0;
          lw1[s2] = (s2 < c1) ? wS[r1][s2] : 0.0;
          li1[s2] = (s2 < c1) ? idxS[r1][s2] : 0;
        }
      }
      #pragma unroll 1
      for (int pair = 0; pair < 2; ++pair) {
        // G <- L * G : per COLUMN (one wave per column), in place.
        for (int c = wv8; c < NN; c += 8) {
          double o0 = 0.0, o1 = 0.0;
          #pragma unroll
          for (int s2 = 0; s2 < 7; ++s2) o0 = fma(lw0[s2], G[li0[s2] * GS + c], o0);
          #pragma unroll
          for (int s2 = 0; s2 < 7; ++s2) o1 = fma(lw1[s2], G[li1[s2] * GS + c], o1);
          asm volatile("s_waitcnt lgkmcnt(0)" ::: "memory");
          G[ln * GS + c] = o0;
          if (h2) G[i2 * GS + c] = o1;
        }
        __syncthreads();
        // G <- G * L^T : per ROW (one wave per row), in place.
        for (int r = wv8; r < NN; r += 8) {
          double o0 = 0.0, o1 = 0.0;
          #pragma unroll
          for (int s2 = 0; s2 < 7; ++s2) o0 = fma(lw0[s2], G[r * GS + li0[s2]], o0);
          #pragma unroll
          for (int s2 = 0; s2 < 7; ++s2) o1 = fma(lw1[s2], G[r * GS + li1[s2]], o1);
          asm volatile("s_waitcnt lgkmcnt(0)" ::: "memory");
          G[r * GS + ln] = o0;
          if (h2) G[r * GS + i2] = o1;
        }
        __syncthreads();
      }
    }

    if (hop == KHOP - 1) {
      // final gram out (compact stride 100)
      for (int e = t; e < NN * NN; e += 512) Gf[e] = G[(e / NN) * GS + (e % NN)];
      __syncthreads();
      // ---- dense L^2 into G (sparse scatter, ascending k order) ----
      if (t < NN) {
        for (int j = 0; j < NN; ++j) G[t * GS + j] = 0.0;
        int cnt = cntS[t];
        for (int s2 = 0; s2 < cnt; ++s2) {
          double w1 = wS[t][s2]; int k = idxS[t][s2];
          int c2 = cntS[k];
          for (int t2 = 0; t2 < c2; ++t2)
            G[t * GS + idxS[k][t2]] += w1 * wS[k][t2];
        }
      }
      __syncthreads();
      // ---- W = build_graph(build_graph(L^2)) ----
      for (int rep = 0; rep < 2; ++rep) {
        if (t < NN) G[t * GS + t] = 0.0;
        __syncthreads();
        if (t < NN) {
          double s = 0.0;
          for (int j = 0; j < NN; ++j) s += G[t * GS + j];
          Dsh[t] = 1.0 / sqrt(s);
        }
        __syncthreads();
        for (int e = t; e < NN * NN; e += 512) {
          int i = e / NN, j = e % NN;
          G[i * GS + j] = (Dsh[j] * G[i * GS + j]) * Dsh[i];
        }
        __syncthreads();
      }
      // M = I - 0.7*W
      for (int e = t; e < NN * NN; e += 512) {
        int i = e / NN, j = e % NN;
        G[i * GS + j] = ((i == j) ? 1.0 : 0.0) - 0.7 * G[i * GS + j];
      }
      __syncthreads();
      // ---- Gauss-Jordan sweep inverse in LDS ----
      for (int k = 0; k < NN; ++k) {
        if (t < NN) { rowk[t] = G[k * GS + t]; colk[t] = G[t * GS + k]; }
        __syncthreads();
        double pinv = 1.0 / rowk[k];
        for (int e = t; e < NN * NN; e += 512) {
          int i = e / NN, j = e % NN;
          double v;
          if (i == k)      v = (j == k) ? pinv : rowk[j] * pinv;
          else if (j == k) v = -(colk[i] * pinv);
          else             v = G[i * GS + j] - colk[i] * (rowk[j] * pinv);
          G[i * GS + j] = v;
        }
        __syncthreads();
      }
      for (int e = t; e < NN * NN; e += 512) Inv[e] = G[(e / NN) * GS + (e % NN)];
    }
  }
}

// =====================================================================
// Kernel 2: epochs + lockstep sinkhorn. This round: hierarchical barrier
// release (leaders-only global spin, per-bucket relaxed broadcast).
// =====================================================================
__global__ __launch_bounds__(256, 2) void k2_epochs(const int* __restrict__ ys,
                                                    const int* __restrict__ yq,
                                                    char* __restrict__ wsb,
                                                    float* __restrict__ out) {
  const int b = blockIdx.x;
  const double* G   = (const double*)(wsb + CTRL_BYTES) + (size_t)b * EP_DBL;
  const double* Inv = G + INV_OFF;
  unsigned* ctrlu = (unsigned*)wsb;

  __shared__ double Z[NN * WAYS];
  __shared__ double gvF[WAYS * NN];
  __shared__ double pbuf[4][WAYS * NN];
  __shared__ double betaS[WAYS][NN];
  __shared__ double nrmS[NN];
  __shared__ double csv[WAYS], pnS[WAYS];
  __shared__ int ysS[NSUP];
  __shared__ unsigned Tsh;
  __shared__ int redi;

  const int t  = threadIdx.x;
  const int wv = t >> 6, ln = t & 63;
  unsigned rnd = 0;

  if (t < NSUP) ysS[t] = ys[b * NSUP + t];
  if (t < NN)   nrmS[t] = G[t * NN + t];
  for (int e = t; e < WAYS * NN; e += 256) {
    int w = e / NN, n = e % NN;
    betaS[w][n] = (n >= w * 5 && n < w * 5 + 5) ? 0.2 : 0.0;
  }
  __syncthreads();

  auto sinkhorn = [&](int base, int n, double cval, bool clamp) {
    const bool own = (wv == 0);
    const int r0 = ln, r1 = ln + 64;
    const bool h1 = (r1 < n);
    double p0[WAYS], p1[WAYS];
    double up0 = 0.0, up1 = 0.0, u0 = 0.0, u1 = 0.0;
    int aflag = 0;
    int m = 0; int ysq = -1;
    if (own) {
      #pragma unroll
      for (int w = 0; w < WAYS; ++w) {
        p0[w] = Z[(base + r0) * WAYS + w];
        p1[w] = h1 ? Z[(base + r1) * WAYS + w] : 0.0;
      }
      if (clamp && r0 < NSUP) ysq = ysS[r0];
      u0 = p0[0] + p0[1] + p0[2] + p0[3] + p0[4];
      if (h1) u1 = p1[0] + p1[1] + p1[2] + p1[3] + p1[4];
      double dl = fabs(up0 - u0);
      if (h1) dl = fmax(dl, fabs(up1 - u1));
      aflag = __any(dl > 1e-3);
    }
    unsigned target = 0;
    for (;;) {
      if (own) {
        while (m < 1000 && ((unsigned)m < target || aflag)) {
          double i0 = frcp(u0);
          #pragma unroll
          for (int w = 0; w < WAYS; ++w) p0[w] *= i0;
          up0 = u0;
          if (h1) {
            double i1 = frcp(u1);
            #pragma unroll
            for (int w = 0; w < WAYS; ++w) p1[w] *= i1;
            up1 = u1;
          }
          #pragma unroll
          for (int w = 0; w < WAYS; ++w) {
            double s = wsum64d_fast(p0[w] + (h1 ? p1[w] : 0.0));
            double f = cval * frcp(s);
            p0[w] *= f;
            if (h1) p1[w] *= f;
          }
          if (clamp && r0 < NSUP) {
            #pragma unroll
            for (int w = 0; w < WAYS; ++w) p0[w] = (ysq == w) ? 1.0 : 0.0;
          }
          ++m;
          u0 = p0[0] + p0[1] + p0[2] + p0[3] + p0[4];
          if (h1) u1 = p1[0] + p1[1] + p1[2] + p1[3] + p1[4];
          double dl = fabs(up0 - u0);
          if (h1) dl = fmax(dl, fabs(up1 - u1));
          aflag = __any(dl > 1e-3);
        }
      }
      __syncthreads();
      if (t == 0) Tsh = grid_barrier_max(ctrlu, b, rnd, (unsigned)m);
      __syncthreads();
      ++rnd;
      unsigned T = Tsh;
      if (T == target) break;
      target = T;
    }
    if (own) {
      #pragma unroll
      for (int w = 0; w < WAYS; ++w) {
        Z[(base + r0) * WAYS + w] = p0[w];
        if (h1) Z[(base + r1) * WAYS + w] = p1[w];
      }
    }
    __syncthreads();
  };

  for (int epi = 0; epi <= NEPOCH; ++epi) {
    // gv[w][r] = sum_k G[r][k]*beta[w][k]  (k split over waves)
    {
      double a0[WAYS], a1[WAYS];
      #pragma unroll
      for (int w = 0; w < WAYS; ++w) { a0[w] = 0.0; a1[w] = 0.0; }
      int k0 = wv * 25;
      for (int kk = 0; kk < 25; ++kk) {
        int k = k0 + kk;
        double g0 = G[(size_t)k * NN + ln];
        double g1 = (ln < NN - 64) ? G[(size_t)k * NN + 64 + ln] : 0.0;
        #pragma unroll
        for (int w = 0; w < WAYS; ++w) {
          double bw = betaS[w][k];
          a0[w] = fma(g0, bw, a0[w]);
          a1[w] = fma(g1, bw, a1[w]);
        }
      }
      #pragma unroll
      for (int w = 0; w < WAYS; ++w) {
        pbuf[wv][w * NN + ln] = a0[w];
        if (ln < NN - 64) pbuf[wv][w * NN + 64 + ln] = a1[w];
      }
    }
    __syncthreads();
    for (int e = t; e < WAYS * NN; e += 256)
      gvF[e] = ((pbuf[0][e] + pbuf[1][e]) + pbuf[2][e]) + pbuf[3][e];
    __syncthreads();
    if (t < WAYS) {
      double s = 0.0;
      for (int n = 0; n < NN; ++n) s = fma(betaS[t][n], gvF[t * NN + n], s);
      pnS[t] = s;
    }
    __syncthreads();
    for (int e = t; e < NQ * WAYS; e += 256) {
      int r = NSUP + e / WAYS, w = e % WAYS;
      double d = (nrmS[r] + pnS[w]) - 2.0 * gvF[w * NN + r];
      Z[r * WAYS + w] = exp(-10.0 * (d > 0.0 ? d : 0.0));
    }
    __syncthreads();
    sinkhorn(NSUP, NQ, 15.0, false);

    if (epi == NEPOCH) {
      if (t == 0) redi = 0;
      __syncthreads();
      if (t < NQ) {
        int row = NSUP + t;
        double bv = Z[row * WAYS + 0]; int am = 0;
        #pragma unroll
        for (int w = 1; w < WAYS; ++w) {
          double v = Z[row * WAYS + w];
          if (v > bv) { bv = v; am = w; }
        }
        if (am == yq[b * NQ + t]) atomicAdd(&redi, 1);
      }
      __syncthreads();
      if (t == 0) out[b] = (float)((double)redi / 75.0);
    } else {
      if (t < NSUP) {
        #pragma unroll
        for (int w = 0; w < WAYS; ++w) Z[t * WAYS + w] = (ysS[t] == w) ? 1.0 : 0.0;
      }
      __syncthreads();
      for (int r = wv; r < NN; r += 4) {
        double a0 = 0, a1 = 0, a2 = 0, a3 = 0, a4 = 0;
        for (int k = ln; k < NN; k += 64) {
          double iv = Inv[(size_t)r * NN + k];
          a0 = fma(iv, Z[k * WAYS + 0], a0);
          a1 = fma(iv, Z[k * WAYS + 1], a1);
          a2 = fma(iv, Z[k * WAYS + 2], a2);
          a3 = fma(iv, Z[k * WAYS + 3], a3);
          a4 = fma(iv, Z[k * WAYS + 4], a4);
        }
        a0 = wsum64d_fast(a0); a1 = wsum64d_fast(a1); a2 = wsum64d_fast(a2);
        a3 = wsum64d_fast(a3); a4 = wsum64d_fast(a4);
        if (ln == 0) {
          pbuf[0][r * WAYS + 0] = a0; pbuf[0][r * WAYS + 1] = a1;
          pbuf[0][r * WAYS + 2] = a2; pbuf[0][r * WAYS + 3] = a3;
          pbuf[0][r * WAYS + 4] = a4;
        }
      }
      __syncthreads();
      for (int e = t; e < NN * WAYS; e += 256) Z[e] = pbuf[0][e];
      __syncthreads();
      sinkhorn(0, NN, 20.0, true);
      if (t < WAYS) {
        double s = 0.0;
        for (int r = 0; r < NN; ++r) s += Z[r * WAYS + t];
        csv[t] = s;
      }
      __syncthreads();
      for (int e = t; e < NN * WAYS; e += 256) {
        int n = e / WAYS, w = e % WAYS;
        double nb = Z[n * WAYS + w] / csv[w];
        betaS[w][n] = 0.4 * betaS[w][n] + 0.6 * nb;
      }
      __syncthreads();
    }
  }
}

extern "C" void kernel_launch(void* const* d_in, const int* in_sizes, int n_in,
                              void* d_out, int out_size, void* d_ws, size_t ws_size,
                              hipStream_t stream) {
  const float* xs = (const float*)d_in[0];
  const float* xq = (const float*)d_in[1];
  const int*   ys = (const int*)d_in[2];
  const int*   yq = (const int*)d_in[3];
  float* out = (float*)d_out;
  char* ws   = (char*)d_ws;

  hipMemsetAsync(d_ws, 0, CTRL_BYTES, stream);

  (void)hipFuncSetAttribute((const void*)k1_lds,
                            hipFuncAttributeMaxDynamicSharedMemorySize,
                            DYN_LDS_BYTES);
  hipLaunchKernelGGL(k1_lds, dim3(B_RUNS), dim3(512), DYN_LDS_BYTES, stream, xs, xq, ws);
  hipLaunchKernelGGL(k2_epochs, dim3(B_RUNS), dim3(256), 0, stream, ys, yq, ws, out);
}

// Round 3
// 2796.317 us; speedup vs baseline: 1.5673x; 1.1077x over previous
//
#include <hip/hip_runtime.h>

// ---------------- problem constants ----------------
#define B_RUNS 500
#define WAYS   5
#define NSUP   25
#define NQ     75
#define NN     100
#define DIM    640
#define TOPK   6
#define KHOP   4
#define NEPOCH 10

// ---------------- barrier control region ----------------
#define CTRL_BYTES 262144
#define NBK    20                 // buckets
#define BPB    25                 // blocks per bucket (500/20)
#define NROUND 1024
#define READYB 0x80000000u

// per-episode doubles: Gf [10000] | Inv [10000]
#define EP_DBL   30016
#define GF_OFF   0
#define INV_OFF  10000

// k1 LDS: G padded to stride 101 (bank-conflict mitigation for column pass)
#define GS   101
#define GOFF (NN * GS)                       // 10100 doubles
#define DYN_LDS_DBL  (GOFF + 3232)           // + 2-team gram staging
#define DYN_LDS_BYTES (DYN_LDS_DBL * 8)      // 106656 B

#if defined(__has_builtin)
#if __has_builtin(__builtin_amdgcn_permlane32_swap)
#define HAVE_PLSWAP 1
#endif
#endif

// ---------------- fast wave-64 helpers ----------------
template <int CTRL>
__device__ __forceinline__ double dpp_add(double v) {
  union { double d; int i[2]; } s, r;
  s.d = v;
  r.i[0] = __builtin_amdgcn_update_dpp(0, s.i[0], CTRL, 0xF, 0xF, false);
  r.i[1] = __builtin_amdgcn_update_dpp(0, s.i[1], CTRL, 0xF, 0xF, false);
  return v + r.d;
}

template <int PAT>
__device__ __forceinline__ double swz_add(double v) {
  union { double d; int i[2]; } s, r;
  s.d = v;
  r.i[0] = __builtin_amdgcn_ds_swizzle(s.i[0], PAT);
  r.i[1] = __builtin_amdgcn_ds_swizzle(s.i[1], PAT);
  return v + r.d;
}

// lane i <-> lane i+32 exchange + add (VALU permlane instead of LDS bpermute)
__device__ __forceinline__ double swap32_add(double v) {
#ifdef HAVE_PLSWAP
  union { double d; int i[2]; } s; s.d = v;
  auto r0 = __builtin_amdgcn_permlane32_swap(s.i[0], s.i[0], false, false);
  auto r1 = __builtin_amdgcn_permlane32_swap(s.i[1], s.i[1], false, false);
  union { double d; int i[2]; } a, b;
  a.i[0] = r0[0]; a.i[1] = r1[0];
  b.i[0] = r0[1]; b.i[1] = r1[1];
  return a.d + b.d;       // lane l: x[l&31] + x[(l&31)+32] == x[l] + x[l^32]
#else
  return v + __shfl_xor(v, 32, 64);
#endif
}

// full 64-lane sum: 4 DPP row-rotate adds + xor16 swizzle + permlane32 swap,
// then broadcast lane 0 so the value is uniform across lanes.
__device__ __forceinline__ double wsum64d_fast(double v) {
  v = dpp_add<0x121>(v);     // row_ror:1
  v = dpp_add<0x122>(v);     // row_ror:2
  v = dpp_add<0x124>(v);     // row_ror:4
  v = dpp_add<0x128>(v);     // row_ror:8  -> every lane holds its 16-row sum
  v = swz_add<0x401F>(v);    // xor 16 within 32
  v = swap32_add(v);         // xor 32
  union { double d; unsigned u[2]; } s; s.d = v;
  s.u[0] = __builtin_amdgcn_readfirstlane(s.u[0]);
  s.u[1] = __builtin_amdgcn_readfirstlane(s.u[1]);
  return s.d;
}

// fast f64 reciprocal: hw rcp seed + 2 Newton steps (<= 1 ulp)
__device__ __forceinline__ double frcp(double x) {
#if __has_builtin(__builtin_amdgcn_rcp)
  double r = __builtin_amdgcn_rcp(x);
#else
  double r = (double)(1.0f / (float)x);
#endif
  double e = fma(-x, r, 1.0);
  r = fma(r, e, r);
  e = fma(-x, r, 1.0);
  r = fma(r, e, r);
  return r;
}

// 2-level grid barrier + global max of payload, hierarchical release.
// Leaders spin on the global line (s_sleep 2); non-leaders spin RELAXED on a
// per-bucket flag with longer backoff (s_sleep 4) to cut coherence traffic.
__device__ unsigned grid_barrier_max(unsigned* ctrlu, int b, unsigned rnd, unsigned lm) {
  unsigned r = rnd < (NROUND - 1) ? rnd : (NROUND - 1);
  const int bk = b % NBK;
  unsigned* barr  = ctrlu + bk * NROUND + r;
  unsigned* bmax  = ctrlu + (NBK + bk) * NROUND + r;
  unsigned* marr  = ctrlu + 2 * NBK * NROUND + r;
  unsigned* mmax  = ctrlu + 2 * NBK * NROUND + NROUND + r;
  unsigned* bflag = ctrlu + (2 * NBK + 2) * NROUND + bk * NROUND + r;

  __hip_atomic_fetch_max(bmax, lm, __ATOMIC_RELAXED, __HIP_MEMORY_SCOPE_AGENT);
  unsigned a = __hip_atomic_fetch_add(barr, 1u, __ATOMIC_ACQ_REL, __HIP_MEMORY_SCOPE_AGENT);
  long sp = 0;
  if (a == (unsigned)(BPB - 1)) {
    unsigned bm = __hip_atomic_load(bmax, __ATOMIC_RELAXED, __HIP_MEMORY_SCOPE_AGENT);
    __hip_atomic_fetch_max(mmax, bm, __ATOMIC_RELAXED, __HIP_MEMORY_SCOPE_AGENT);
    __hip_atomic_fetch_add(marr, 1u, __ATOMIC_ACQ_REL, __HIP_MEMORY_SCOPE_AGENT);
    while (__hip_atomic_load(marr, __ATOMIC_RELAXED, __HIP_MEMORY_SCOPE_AGENT) < (unsigned)NBK) {
      __builtin_amdgcn_s_sleep(2);
      if (++sp > 50000000L) break;   // safety: terminate, don't hang
    }
    __builtin_amdgcn_fence(__ATOMIC_ACQUIRE, "agent");
    unsigned g = __hip_atomic_load(mmax, __ATOMIC_RELAXED, __HIP_MEMORY_SCOPE_AGENT);
    __hip_atomic_store(bflag, g | READYB, __ATOMIC_RELEASE, __HIP_MEMORY_SCOPE_AGENT);
    return g;
  } else {
    unsigned f;
    while (!((f = __hip_atomic_load(bflag, __ATOMIC_RELAXED, __HIP_MEMORY_SCOPE_AGENT)) & READYB)) {
      __builtin_amdgcn_s_sleep(4);
      if (++sp > 50000000L) break;   // safety: terminate, don't hang
    }
    __builtin_amdgcn_fence(__ATOMIC_ACQUIRE, "agent");
    return f & ~READYB;
  }
}

// =====================================================================
// Kernel 1 (gram-space), 1024 threads (16 waves/CU for latency hiding).
// Gram: 2 teams x 512 threads, 20x25 grid, 5x4 register tile (exact
// 100x100 coverage, same per-output k-order as before -> bit-identical).
// Then per hop: top-6 -> sparse L -> in-place LDS congruence. Hop 3:
// Gf, dense L^2, W chain, M = I-0.7W, Gauss-Jordan inverse -> Inv.
// =====================================================================
__global__ __launch_bounds__(1024) void k1_lds(const float* __restrict__ xs,
                                               const float* __restrict__ xq,
                                               char* __restrict__ wsb) {
  extern __shared__ double dynb[];
  double* G  = dynb;            // 100 x 101 (padded stride)
  double* ST = dynb + GOFF;     // 2 teams x 1616 gram staging

  const int b = blockIdx.x;
  double* ep  = (double*)(wsb + CTRL_BYTES) + (size_t)b * EP_DBL;
  double* Gf  = ep + GF_OFF;
  double* Inv = ep + INV_OFF;

  __shared__ double nsh[NN], Dsh[NN], rowk[NN], colk[NN];
  __shared__ double wS[NN][7];
  __shared__ int    idxS[NN][7];
  __shared__ int    cntS[NN];

  const int t  = threadIdx.x;
  const int tm = t >> 9;              // team 0/1 (512 threads each)
  const int tt = t & 511;
  const int tx = tt % 25;             // col group 0..24
  const int ty = tt / 25;             // row group 0..20 (>=20 idle)
  const bool act = (ty < 20);
  const int tyc = act ? ty : 19;      // clamped for safe addresses
  double* STt = ST + tm * 1616;

  int ia[5], ja[4];
  #pragma unroll
  for (int a = 0; a < 5; ++a) ia[a] = tyc + 20 * a;   // rows: exact partition
  #pragma unroll
  for (int c = 0; c < 4; ++c) ja[c] = tx + 25 * c;    // cols: exact partition

  // ---- initial gram G0 = F F^T from fp32 inputs (2-team split-K, b128 pairs) ----
  {
    double acc[5][4];
    #pragma unroll
    for (int a = 0; a < 5; ++a)
      #pragma unroll
      for (int c = 0; c < 4; ++c) acc[a][c] = 0.0;
    const float* xsb = xs + (size_t)b * NSUP * DIM;
    const float* xqb = xq + (size_t)b * NQ * DIM;
    for (int chunk = 0; chunk < 20; ++chunk) {
      int k0 = (chunk * 2 + tm) * 16;
      for (int e = tt; e < NN * 16; e += 512) {
        int r = e >> 4, km = e & 15;
        int k = k0 + km;
        float v = (r < NSUP) ? xsb[r * DIM + k] : xqb[(r - NSUP) * DIM + k];
        STt[(km >> 1) * 202 + 2 * r + (km & 1)] = (double)v;
      }
      __syncthreads();
      #pragma unroll 2
      for (int m = 0; m < 8; ++m) {
        double2 rv[5], cv[4];
        #pragma unroll
        for (int a = 0; a < 5; ++a) rv[a] = *(const double2*)(STt + m * 202 + 2 * ia[a]);
        #pragma unroll
        for (int c = 0; c < 4; ++c) cv[c] = *(const double2*)(STt + m * 202 + 2 * ja[c]);
        #pragma unroll
        for (int a = 0; a < 5; ++a)
          #pragma unroll
          for (int c = 0; c < 4; ++c) {
            acc[a][c] = fma(rv[a].x, cv[c].x, acc[a][c]);
            acc[a][c] = fma(rv[a].y, cv[c].y, acc[a][c]);
          }
      }
      __syncthreads();
    }
    if (tm == 1 && act) {
      #pragma unroll
      for (int a = 0; a < 5; ++a)
        #pragma unroll
        for (int c = 0; c < 4; ++c)
          G[ia[a] * GS + ja[c]] = acc[a][c];
    }
    __syncthreads();
    if (tm == 0 && act) {
      #pragma unroll
      for (int a = 0; a < 5; ++a)
        #pragma unroll
        for (int c = 0; c < 4; ++c)
          G[ia[a] * GS + ja[c]] = acc[a][c] + G[ia[a] * GS + ja[c]];
    }
    __syncthreads();
  }

  for (int hop = 0; hop < KHOP; ++hop) {
    if (t < NN) nsh[t] = G[t * GS + t];
    __syncthreads();
    // ---- top-6 per row by clamped distance (ascending; ties -> lowest index) ----
    int kj[TOPK]; double ke[TOPK];
    if (t < NN) {
      unsigned long long m0 = 0ull, m1 = 0ull;
      const double nt = nsh[t];
      for (int s = 0; s < TOPK; ++s) {
        double best = 1e300; int bj = 0;
        for (int j = 0; j < NN; ++j) {
          unsigned long long bit = (j < 64) ? ((m0 >> j) & 1ull) : ((m1 >> (j - 64)) & 1ull);
          if (bit) continue;
          double d = (nt + nsh[j]) - 2.0 * G[t * GS + j];
          d = d > 0.0 ? d : 0.0;
          if (d < best) { best = d; bj = j; }     // strict <: lowest index wins ties
        }
        if (bj < 64) m0 |= 1ull << bj; else m1 |= 1ull << (bj - 64);
      }
      // kept entries ascending (lowest set bit first); exp weights; rowsum
      double s = 0.0;
      unsigned long long mm0 = m0, mm1 = m1;
      #pragma unroll
      for (int sidx = 0; sidx < TOPK; ++sidx) {
        int j;
        if (mm0) { j = __ffsll((long long)mm0) - 1; mm0 &= mm0 - 1; }
        else     { j = 64 + __ffsll((long long)mm1) - 1; mm1 &= mm1 - 1; }
        double d = (nt + nsh[j]) - 2.0 * G[t * GS + j];
        d = d > 0.0 ? d : 0.0;
        double e = exp(-10.0 * d);
        kj[sidx] = j; ke[sidx] = e;
        s += e;
      }
      Dsh[t] = 1.0 / sqrt(s);
    }
    __syncthreads();
    // ---- build sparse L row: ascending index, self 0.5 folded/inserted ----
    if (t < NN) {
      int cnt = 0; bool sd = false;
      double dt = Dsh[t];
      #pragma unroll
      for (int sidx = 0; sidx < TOPK; ++sidx) {
        int j = kj[sidx];
        double lw = 0.5 * ((Dsh[j] * ke[sidx]) * dt);
        if (j == t) { lw = 0.5 + lw; sd = true; }
        else if (!sd && j > t) { idxS[t][cnt] = t; wS[t][cnt] = 0.5; ++cnt; sd = true; }
        idxS[t][cnt] = j; wS[t][cnt] = lw; ++cnt;
      }
      if (!sd) { idxS[t][cnt] = t; wS[t][cnt] = 0.5; ++cnt; }
      cntS[t] = cnt;
    }
    __syncthreads();

    // ---- congruence: G <- L (L G L^T) L^T, fully in-place in LDS ----
    {
      const int wv16 = t >> 6, ln = t & 63;
      const int i2 = ln + 64;
      const bool h2 = (i2 < NN);
      const int r1 = h2 ? i2 : 0;
      double lw0[7], lw1[7]; int li0[7], li1[7];
      {
        int c0 = cntS[ln];
        int c1 = h2 ? cntS[r1] : 0;
        #pragma unroll
        for (int s2 = 0; s2 < 7; ++s2) {
          lw0[s2] = (s2 < c0) ? wS[ln][s2] : 0.0;
          li0[s2] = (s2 < c0) ? idxS[ln][s2] : 0;
          lw1[s2] = (s2 < c1) ? wS[r1][s2] : 0.0;
          li1[s2] = (s2 < c1) ? idxS[r1][s2] : 0;
        }
      }
      #pragma unroll 1
      for (int pair = 0; pair < 2; ++pair) {
        // G <- L * G : per COLUMN (one wave per column), in place.
        for (int c = wv16; c < NN; c += 16) {
          double o0 = 0.0, o1 = 0.0;
          #pragma unroll
          for (int s2 = 0; s2 < 7; ++s2) o0 = fma(lw0[s2], G[li0[s2] * GS + c], o0);
          #pragma unroll
          for (int s2 = 0; s2 < 7; ++s2) o1 = fma(lw1[s2], G[li1[s2] * GS + c], o1);
          asm volatile("s_waitcnt lgkmcnt(0)" ::: "memory");
          G[ln * GS + c] = o0;
          if (h2) G[i2 * GS + c] = o1;
        }
        __syncthreads();
        // G <- G * L^T : per ROW (one wave per row), in place.
        for (int r = wv16; r < NN; r += 16) {
          double o0 = 0.0, o1 = 0.0;
          #pragma unroll
          for (int s2 = 0; s2 < 7; ++s2) o0 = fma(lw0[s2], G[r * GS + li0[s2]], o0);
          #pragma unroll
          for (int s2 = 0; s2 < 7; ++s2) o1 = fma(lw1[s2], G[r * GS + li1[s2]], o1);
          asm volatile("s_waitcnt lgkmcnt(0)" ::: "memory");
          G[r * GS + ln] = o0;
          if (h2) G[r * GS + i2] = o1;
        }
        __syncthreads();
      }
    }

    if (hop == KHOP - 1) {
      // final gram out (compact stride 100)
      for (int e = t; e < NN * NN; e += 1024) Gf[e] = G[(e / NN) * GS + (e % NN)];
      __syncthreads();
      // ---- dense L^2 into G (sparse scatter, ascending k order) ----
      if (t < NN) {
        for (int j = 0; j < NN; ++j) G[t * GS + j] = 0.0;
        int cnt = cntS[t];
        for (int s2 = 0; s2 < cnt; ++s2) {
          double w1 = wS[t][s2]; int k = idxS[t][s2];
          int c2 = cntS[k];
          for (int t2 = 0; t2 < c2; ++t2)
            G[t * GS + idxS[k][t2]] += w1 * wS[k][t2];
        }
      }
      __syncthreads();
      // ---- W = build_graph(build_graph(L^2)) ----
      for (int rep = 0; rep < 2; ++rep) {
        if (t < NN) G[t * GS + t] = 0.0;
        __syncthreads();
        if (t < NN) {
          double s = 0.0;
          for (int j = 0; j < NN; ++j) s += G[t * GS + j];
          Dsh[t] = 1.0 / sqrt(s);
        }
        __syncthreads();
        for (int e = t; e < NN * NN; e += 1024) {
          int i = e / NN, j = e % NN;
          G[i * GS + j] = (Dsh[j] * G[i * GS + j]) * Dsh[i];
        }
        __syncthreads();
      }
      // M = I - 0.7*W
      for (int e = t; e < NN * NN; e += 1024) {
        int i = e / NN, j = e % NN;
        G[i * GS + j] = ((i == j) ? 1.0 : 0.0) - 0.7 * G[i * GS + j];
      }
      __syncthreads();
      // ---- Gauss-Jordan sweep inverse in LDS ----
      for (int k = 0; k < NN; ++k) {
        if (t < NN) { rowk[t] = G[k * GS + t]; colk[t] = G[t * GS + k]; }
        __syncthreads();
        double pinv = 1.0 / rowk[k];
        for (int e = t; e < NN * NN; e += 1024) {
          int i = e / NN, j = e % NN;
          double v;
          if (i == k)      v = (j == k) ? pinv : rowk[j] * pinv;
          else if (j == k) v = -(colk[i] * pinv);
          else             v = G[i * GS + j] - colk[i] * (rowk[j] * pinv);
          G[i * GS + j] = v;
        }
        __syncthreads();
      }
      for (int e = t; e < NN * NN; e += 1024) Inv[e] = G[(e / NN) * GS + (e % NN)];
    }
  }
}

// =====================================================================
// Kernel 2: epochs + lockstep sinkhorn. This round: permlane32 butterfly,
// spin backoff, lazy convergence-delta during catch-up.
// =====================================================================
__global__ __launch_bounds__(256, 2) void k2_epochs(const int* __restrict__ ys,
                                                    const int* __restrict__ yq,
                                                    char* __restrict__ wsb,
                                                    float* __restrict__ out) {
  const int b = blockIdx.x;
  const double* G   = (const double*)(wsb + CTRL_BYTES) + (size_t)b * EP_DBL;
  const double* Inv = G + INV_OFF;
  unsigned* ctrlu = (unsigned*)wsb;

  __shared__ double Z[NN * WAYS];
  __shared__ double gvF[WAYS * NN];
  __shared__ double pbuf[4][WAYS * NN];
  __shared__ double betaS[WAYS][NN];
  __shared__ double nrmS[NN];
  __shared__ double csv[WAYS], pnS[WAYS];
  __shared__ int ysS[NSUP];
  __shared__ unsigned Tsh;
  __shared__ int redi;

  const int t  = threadIdx.x;
  const int wv = t >> 6, ln = t & 63;
  unsigned rnd = 0;

  if (t < NSUP) ysS[t] = ys[b * NSUP + t];
  if (t < NN)   nrmS[t] = G[t * NN + t];
  for (int e = t; e < WAYS * NN; e += 256) {
    int w = e / NN, n = e % NN;
    betaS[w][n] = (n >= w * 5 && n < w * 5 + 5) ? 0.2 : 0.0;
  }
  __syncthreads();

  auto sinkhorn = [&](int base, int n, double cval, bool clamp) {
    const bool own = (wv == 0);
    const int r0 = ln, r1 = ln + 64;
    const bool h1 = (r1 < n);
    double p0[WAYS], p1[WAYS];
    double up0 = 0.0, up1 = 0.0, u0 = 0.0, u1 = 0.0;
    int aflag = 0;
    int m = 0; int ysq = -1;
    if (own) {
      #pragma unroll
      for (int w = 0; w < WAYS; ++w) {
        p0[w] = Z[(base + r0) * WAYS + w];
        p1[w] = h1 ? Z[(base + r1) * WAYS + w] : 0.0;
      }
      if (clamp && r0 < NSUP) ysq = ysS[r0];
      u0 = p0[0] + p0[1] + p0[2] + p0[3] + p0[4];
      if (h1) u1 = p1[0] + p1[1] + p1[2] + p1[3] + p1[4];
      double dl = fabs(up0 - u0);
      if (h1) dl = fmax(dl, fabs(up1 - u1));
      aflag = __any(dl > 1e-3);
    }
    unsigned target = 0;
    for (;;) {
      if (own) {
        while (m < 1000 && ((unsigned)m < target || aflag)) {
          double i0 = frcp(u0);
          #pragma unroll
          for (int w = 0; w < WAYS; ++w) p0[w] *= i0;
          up0 = u0;
          if (h1) {
            double i1 = frcp(u1);
            #pragma unroll
            for (int w = 0; w < WAYS; ++w) p1[w] *= i1;
            up1 = u1;
          }
          #pragma unroll
          for (int w = 0; w < WAYS; ++w) {
            double s = wsum64d_fast(p0[w] + (h1 ? p1[w] : 0.0));
            double f = cval * frcp(s);
            p0[w] *= f;
            if (h1) p1[w] *= f;
          }
          if (clamp && r0 < NSUP) {
            #pragma unroll
            for (int w = 0; w < WAYS; ++w) p0[w] = (ysq == w) ? 1.0 : 0.0;
          }
          ++m;
          u0 = p0[0] + p0[1] + p0[2] + p0[3] + p0[4];
          if (h1) u1 = p1[0] + p1[1] + p1[2] + p1[3] + p1[4];
          if ((unsigned)m >= target) {     // lazy: delta only matters once caught up
            double dl = fabs(up0 - u0);
            if (h1) dl = fmax(dl, fabs(up1 - u1));
            aflag = __any(dl > 1e-3);
          } else {
            aflag = 1;
          }
        }
      }
      __syncthreads();
      if (t == 0) Tsh = grid_barrier_max(ctrlu, b, rnd, (unsigned)m);
      __syncthreads();
      ++rnd;
      unsigned T = Tsh;
      if (T == target) break;
      target = T;
    }
    if (own) {
      #pragma unroll
      for (int w = 0; w < WAYS; ++w) {
        Z[(base + r0) * WAYS + w] = p0[w];
        if (h1) Z[(base + r1) * WAYS + w] = p1[w];
      }
    }
    __syncthreads();
  };

  for (int epi = 0; epi <= NEPOCH; ++epi) {
    // gv[w][r] = sum_k G[r][k]*beta[w][k]  (k split over waves)
    {
      double a0[WAYS], a1[WAYS];
      #pragma unroll
      for (int w = 0; w < WAYS; ++w) { a0[w] = 0.0; a1[w] = 0.0; }
      int k0 = wv * 25;
      for (int kk = 0; kk < 25; ++kk) {
        int k = k0 + kk;
        double g0 = G[(size_t)k * NN + ln];
        double g1 = (ln < NN - 64) ? G[(size_t)k * NN + 64 + ln] : 0.0;
        #pragma unroll
        for (int w = 0; w < WAYS; ++w) {
          double bw = betaS[w][k];
          a0[w] = fma(g0, bw, a0[w]);
          a1[w] = fma(g1, bw, a1[w]);
        }
      }
      #pragma unroll
      for (int w = 0; w < WAYS; ++w) {
        pbuf[wv][w * NN + ln] = a0[w];
        if (ln < NN - 64) pbuf[wv][w * NN + 64 + ln] = a1[w];
      }
    }
    __syncthreads();
    for (int e = t; e < WAYS * NN; e += 256)
      gvF[e] = ((pbuf[0][e] + pbuf[1][e]) + pbuf[2][e]) + pbuf[3][e];
    __syncthreads();
    if (t < WAYS) {
      double s = 0.0;
      for (int n = 0; n < NN; ++n) s = fma(betaS[t][n], gvF[t * NN + n], s);
      pnS[t] = s;
    }
    __syncthreads();
    for (int e = t; e < NQ * WAYS; e += 256) {
      int r = NSUP + e / WAYS, w = e % WAYS;
      double d = (nrmS[r] + pnS[w]) - 2.0 * gvF[w * NN + r];
      Z[r * WAYS + w] = exp(-10.0 * (d > 0.0 ? d : 0.0));
    }
    __syncthreads();
    sinkhorn(NSUP, NQ, 15.0, false);

    if (epi == NEPOCH) {
      if (t == 0) redi = 0;
      __syncthreads();
      if (t < NQ) {
        int row = NSUP + t;
        double bv = Z[row * WAYS + 0]; int am = 0;
        #pragma unroll
        for (int w = 1; w < WAYS; ++w) {
          double v = Z[row * WAYS + w];
          if (v > bv) { bv = v; am = w; }
        }
        if (am == yq[b * NQ + t]) atomicAdd(&redi, 1);
      }
      __syncthreads();
      if (t == 0) out[b] = (float)((double)redi / 75.0);
    } else {
      if (t < NSUP) {
        #pragma unroll
        for (int w = 0; w < WAYS; ++w) Z[t * WAYS + w] = (ysS[t] == w) ? 1.0 : 0.0;
      }
      __syncthreads();
      for (int r = wv; r < NN; r += 4) {
        double a0 = 0, a1 = 0, a2 = 0, a3 = 0, a4 = 0;
        for (int k = ln; k < NN; k += 64) {
          double iv = Inv[(size_t)r * NN + k];
          a0 = fma(iv, Z[k * WAYS + 0], a0);
          a1 = fma(iv, Z[k * WAYS + 1], a1);
          a2 = fma(iv, Z[k * WAYS + 2], a2);
          a3 = fma(iv, Z[k * WAYS + 3], a3);
          a4 = fma(iv, Z[k * WAYS + 4], a4);
        }
        a0 = wsum64d_fast(a0); a1 = wsum64d_fast(a1); a2 = wsum64d_fast(a2);
        a3 = wsum64d_fast(a3); a4 = wsum64d_fast(a4);
        if (ln == 0) {
          pbuf[0][r * WAYS + 0] = a0; pbuf[0][r * WAYS + 1] = a1;
          pbuf[0][r * WAYS + 2] = a2; pbuf[0][r * WAYS + 3] = a3;
          pbuf[0][r * WAYS + 4] = a4;
        }
      }
      __syncthreads();
      for (int e = t; e < NN * WAYS; e += 256) Z[e] = pbuf[0][e];
      __syncthreads();
      sinkhorn(0, NN, 20.0, true);
      if (t < WAYS) {
        double s = 0.0;
        for (int r = 0; r < NN; ++r) s += Z[r * WAYS + t];
        csv[t] = s;
      }
      __syncthreads();
      for (int e = t; e < NN * WAYS; e += 256) {
        int n = e / WAYS, w = e % WAYS;
        double nb = Z[n * WAYS + w] / csv[w];
        betaS[w][n] = 0.4 * betaS[w][n] + 0.6 * nb;
      }
      __syncthreads();
    }
  }
}

extern "C" void kernel_launch(void* const* d_in, const int* in_sizes, int n_in,
                              void* d_out, int out_size, void* d_ws, size_t ws_size,
                              hipStream_t stream) {
  const float* xs = (const float*)d_in[0];
  const float* xq = (const float*)d_in[1];
  const int*   ys = (const int*)d_in[2];
  const int*   yq = (const int*)d_in[3];
  float* out = (float*)d_out;
  char* ws   = (char*)d_ws;

  hipMemsetAsync(d_ws, 0, CTRL_BYTES, stream);

  (void)hipFuncSetAttribute((const void*)k1_lds,
                            hipFuncAttributeMaxDynamicSharedMemorySize,
                            DYN_LDS_BYTES);
  hipLaunchKernelGGL(k1_lds, dim3(B_RUNS), dim3(1024), DYN_LDS_BYTES, stream, xs, xq, ws);
  hipLaunchKernelGGL(k2_epochs, dim3(B_RUNS), dim3(256), 0, stream, ys, yq, ws, out);
}

// Round 5
// 1888.730 us; speedup vs baseline: 2.3204x; 1.4805x over previous
//
#include <hip/hip_runtime.h>

// ---------------- problem constants ----------------
#define B_RUNS 500
#define WAYS   5
#define NSUP   25
#define NQ     75
#define NN     100
#define DIM    640
#define TOPK   6
#define KHOP   4
#define NEPOCH 10

// ---------------- barrier control region ----------------
#define CTRL_BYTES 262144
#define KB2    250                // k2 blocks (2 episodes each)
#define NBK    25                 // buckets
#define BPB    10                 // blocks per bucket (250/25)
#define NROUND 512
#define READYB 0x80000000u
// ctrl words: barr[25][512] | bmax[25][512] | marr[512] | mmax[512] | bflag[25][512]
// = 77*512 words = 157,696 B <= 256 KB

// per-episode FLOATS: Gf [10000] f32 | Inv [10000] f32
#define EP_FLT   20224
#define GF_OFF   0
#define INV_OFF  10000

// k1 LDS: G (f64, stride 101) + f32 gram staging (2 teams x 1616 floats)
#define GS   101
#define GOFF (NN * GS)                        // 10100 doubles
#define DYN_LDS_BYTES (GOFF * 8 + 2 * 1616 * 4)   // 80800 + 12928 = 93728 B

#if defined(__has_builtin)
#if __has_builtin(__builtin_amdgcn_permlane32_swap)
#define HAVE_PLSWAP 1
#endif
#endif

// ---------------- fast wave-64 f32 helpers ----------------
template <int CTRL>
__device__ __forceinline__ float dpp_addf(float v) {
  int r = __builtin_amdgcn_update_dpp(0, __float_as_int(v), CTRL, 0xF, 0xF, false);
  return v + __int_as_float(r);
}
template <int PAT>
__device__ __forceinline__ float swz_addf(float v) {
  return v + __int_as_float(__builtin_amdgcn_ds_swizzle(__float_as_int(v), PAT));
}
__device__ __forceinline__ float swap32_addf(float v) {
#ifdef HAVE_PLSWAP
  int x = __float_as_int(v);
  auto r = __builtin_amdgcn_permlane32_swap(x, x, false, false);
  return __int_as_float(r[0]) + __int_as_float(r[1]);
#else
  return v + __shfl_xor(v, 32, 64);
#endif
}
// full 64-lane f32 sum, result uniform across lanes
__device__ __forceinline__ float wsum64f_fast(float v) {
  v = dpp_addf<0x121>(v);    // row_ror:1
  v = dpp_addf<0x122>(v);    // row_ror:2
  v = dpp_addf<0x124>(v);    // row_ror:4
  v = dpp_addf<0x128>(v);    // row_ror:8
  v = swz_addf<0x401F>(v);   // xor 16
  v = swap32_addf(v);        // xor 32
  return __int_as_float(__builtin_amdgcn_readfirstlane(__float_as_int(v)));
}
// fast f32 reciprocal: hw rcp + 1 Newton
__device__ __forceinline__ float frcpf(float x) {
#if __has_builtin(__builtin_amdgcn_rcpf)
  float r = __builtin_amdgcn_rcpf(x);
#else
  float r = 1.0f / x;
#endif
  float e = fmaf(-x, r, 1.0f);
  r = fmaf(r, e, r);
  return r;
}

// 2-level grid barrier + global max of payload, hierarchical release.
__device__ unsigned grid_barrier_max(unsigned* ctrlu, int b, unsigned rnd, unsigned lm) {
  unsigned r = rnd < (NROUND - 1) ? rnd : (NROUND - 1);
  const int bk = b % NBK;
  unsigned* barr  = ctrlu + bk * NROUND + r;
  unsigned* bmax  = ctrlu + (NBK + bk) * NROUND + r;
  unsigned* marr  = ctrlu + 2 * NBK * NROUND + r;
  unsigned* mmax  = ctrlu + 2 * NBK * NROUND + NROUND + r;
  unsigned* bflag = ctrlu + (2 * NBK + 2) * NROUND + bk * NROUND + r;

  __hip_atomic_fetch_max(bmax, lm, __ATOMIC_RELAXED, __HIP_MEMORY_SCOPE_AGENT);
  unsigned a = __hip_atomic_fetch_add(barr, 1u, __ATOMIC_ACQ_REL, __HIP_MEMORY_SCOPE_AGENT);
  long sp = 0;
  if (a == (unsigned)(BPB - 1)) {
    unsigned bm = __hip_atomic_load(bmax, __ATOMIC_RELAXED, __HIP_MEMORY_SCOPE_AGENT);
    __hip_atomic_fetch_max(mmax, bm, __ATOMIC_RELAXED, __HIP_MEMORY_SCOPE_AGENT);
    __hip_atomic_fetch_add(marr, 1u, __ATOMIC_ACQ_REL, __HIP_MEMORY_SCOPE_AGENT);
    while (__hip_atomic_load(marr, __ATOMIC_RELAXED, __HIP_MEMORY_SCOPE_AGENT) < (unsigned)NBK) {
      __builtin_amdgcn_s_sleep(2);
      if (++sp > 50000000L) break;   // safety: terminate, don't hang
    }
    __builtin_amdgcn_fence(__ATOMIC_ACQUIRE, "agent");
    unsigned g = __hip_atomic_load(mmax, __ATOMIC_RELAXED, __HIP_MEMORY_SCOPE_AGENT);
    __hip_atomic_store(bflag, g | READYB, __ATOMIC_RELEASE, __HIP_MEMORY_SCOPE_AGENT);
    return g;
  } else {
    unsigned f;
    while (!((f = __hip_atomic_load(bflag, __ATOMIC_RELAXED, __HIP_MEMORY_SCOPE_AGENT)) & READYB)) {
      __builtin_amdgcn_s_sleep(4);
      if (++sp > 50000000L) break;   // safety: terminate, don't hang
    }
    __builtin_amdgcn_fence(__ATOMIC_ACQUIRE, "agent");
    return f & ~READYB;
  }
}

// =====================================================================
// Kernel 1 (gram-space), 1024 threads. Gram: 2 teams x 512, 20x25 grid,
// 5x4 f64 register tile (40 VGPR acc -- fits the 128-VGPR budget of a
// 1024-thread block), staging in f32 (f32->f64 conversion exact ->
// bit-identical math, half the LDS bytes). Then per hop: top-6 ->
// sparse L -> in-place LDS congruence. Hop 3: Gf (f32), dense L^2,
// W chain, M = I-0.7W, GJ inverse (f64) -> Inv (f32).
// =====================================================================
__global__ __launch_bounds__(1024) void k1_lds(const float* __restrict__ xs,
                                               const float* __restrict__ xq,
                                               char* __restrict__ wsb) {
  extern __shared__ double dynb[];
  double* G   = dynb;                      // 100 x 101 (padded stride)
  float*  STf = (float*)(dynb + GOFF);     // 2 teams x 1616 f32 staging

  const int b = blockIdx.x;
  float* GfF  = (float*)(wsb + CTRL_BYTES) + (size_t)b * EP_FLT;
  float* InvF = GfF + INV_OFF;

  __shared__ double nsh[NN], Dsh[NN], rowk[NN], colk[NN];
  __shared__ double wS[NN][7];
  __shared__ int    idxS[NN][7];
  __shared__ int    cntS[NN];

  const int t  = threadIdx.x;
  const int tm = t >> 9;              // team 0/1 (512 threads each)
  const int tt = t & 511;
  const int tx = tt % 25;             // col group 0..24
  const int ty = tt / 25;             // row group 0..20 (>=20 idle)
  const bool act = (ty < 20);
  const int tyc = act ? ty : 19;      // clamped for safe addresses
  float* STt = STf + tm * 1616;

  int ia[5], ja[4];
  #pragma unroll
  for (int a = 0; a < 5; ++a) ia[a] = tyc + 20 * a;   // rows: exact partition
  #pragma unroll
  for (int c = 0; c < 4; ++c) ja[c] = tx + 25 * c;    // cols: exact partition

  // ---- initial gram G0 = F F^T (2-team split-K, f32 staged, f64 acc) ----
  {
    double acc[5][4];
    #pragma unroll
    for (int a = 0; a < 5; ++a)
      #pragma unroll
      for (int c = 0; c < 4; ++c) acc[a][c] = 0.0;
    const float* xsb = xs + (size_t)b * NSUP * DIM;
    const float* xqb = xq + (size_t)b * NQ * DIM;
    for (int chunk = 0; chunk < 20; ++chunk) {
      int k0 = (chunk * 2 + tm) * 16;
      for (int e = tt; e < NN * 16; e += 512) {
        int r = e >> 4, km = e & 15;
        int k = k0 + km;
        float v = (r < NSUP) ? xsb[r * DIM + k] : xqb[(r - NSUP) * DIM + k];
        STt[(km >> 1) * 202 + 2 * r + (km & 1)] = v;
      }
      __syncthreads();
      #pragma unroll 2
      for (int m = 0; m < 8; ++m) {
        float2 rv[5], cv[4];
        #pragma unroll
        for (int a = 0; a < 5; ++a) rv[a] = *(const float2*)(STt + m * 202 + 2 * ia[a]);
        #pragma unroll
        for (int c = 0; c < 4; ++c) cv[c] = *(const float2*)(STt + m * 202 + 2 * ja[c]);
        #pragma unroll
        for (int a = 0; a < 5; ++a)
          #pragma unroll
          for (int c = 0; c < 4; ++c) {
            acc[a][c] = fma((double)rv[a].x, (double)cv[c].x, acc[a][c]);
            acc[a][c] = fma((double)rv[a].y, (double)cv[c].y, acc[a][c]);
          }
      }
      __syncthreads();
    }
    if (tm == 1 && act) {
      #pragma unroll
      for (int a = 0; a < 5; ++a)
        #pragma unroll
        for (int c = 0; c < 4; ++c)
          G[ia[a] * GS + ja[c]] = acc[a][c];
    }
    __syncthreads();
    if (tm == 0 && act) {
      #pragma unroll
      for (int a = 0; a < 5; ++a)
        #pragma unroll
        for (int c = 0; c < 4; ++c)
          G[ia[a] * GS + ja[c]] = acc[a][c] + G[ia[a] * GS + ja[c]];
    }
    __syncthreads();
  }

  for (int hop = 0; hop < KHOP; ++hop) {
    if (t < NN) nsh[t] = G[t * GS + t];
    __syncthreads();
    // ---- top-6 per row by clamped distance (ascending; ties -> lowest index) ----
    int kj[TOPK]; double ke[TOPK];
    if (t < NN) {
      unsigned long long m0 = 0ull, m1 = 0ull;
      const double nt = nsh[t];
      for (int s = 0; s < TOPK; ++s) {
        double best = 1e300; int bj = 0;
        for (int j = 0; j < NN; ++j) {
          unsigned long long bit = (j < 64) ? ((m0 >> j) & 1ull) : ((m1 >> (j - 64)) & 1ull);
          if (bit) continue;
          double d = (nt + nsh[j]) - 2.0 * G[t * GS + j];
          d = d > 0.0 ? d : 0.0;
          if (d < best) { best = d; bj = j; }     // strict <: lowest index wins ties
        }
        if (bj < 64) m0 |= 1ull << bj; else m1 |= 1ull << (bj - 64);
      }
      double s = 0.0;
      unsigned long long mm0 = m0, mm1 = m1;
      #pragma unroll
      for (int sidx = 0; sidx < TOPK; ++sidx) {
        int j;
        if (mm0) { j = __ffsll((long long)mm0) - 1; mm0 &= mm0 - 1; }
        else     { j = 64 + __ffsll((long long)mm1) - 1; mm1 &= mm1 - 1; }
        double d = (nt + nsh[j]) - 2.0 * G[t * GS + j];
        d = d > 0.0 ? d : 0.0;
        double e = exp(-10.0 * d);
        kj[sidx] = j; ke[sidx] = e;
        s += e;
      }
      Dsh[t] = 1.0 / sqrt(s);
    }
    __syncthreads();
    // ---- build sparse L row: ascending index, self 0.5 folded/inserted ----
    if (t < NN) {
      int cnt = 0; bool sd = false;
      double dt = Dsh[t];
      #pragma unroll
      for (int sidx = 0; sidx < TOPK; ++sidx) {
        int j = kj[sidx];
        double lw = 0.5 * ((Dsh[j] * ke[sidx]) * dt);
        if (j == t) { lw = 0.5 + lw; sd = true; }
        else if (!sd && j > t) { idxS[t][cnt] = t; wS[t][cnt] = 0.5; ++cnt; sd = true; }
        idxS[t][cnt] = j; wS[t][cnt] = lw; ++cnt;
      }
      if (!sd) { idxS[t][cnt] = t; wS[t][cnt] = 0.5; ++cnt; }
      cntS[t] = cnt;
    }
    __syncthreads();

    // ---- congruence: G <- L (L G L^T) L^T, fully in-place in LDS ----
    {
      const int wv16 = t >> 6, ln = t & 63;
      const int i2 = ln + 64;
      const bool h2 = (i2 < NN);
      const int r1 = h2 ? i2 : 0;
      double lw0[7], lw1[7]; int li0[7], li1[7];
      {
        int c0 = cntS[ln];
        int c1 = h2 ? cntS[r1] : 0;
        #pragma unroll
        for (int s2 = 0; s2 < 7; ++s2) {
          lw0[s2] = (s2 < c0) ? wS[ln][s2] : 0.0;
          li0[s2] = (s2 < c0) ? idxS[ln][s2] : 0;
          lw1[s2] = (s2 < c1) ? wS[r1][s2] : 0.0;
          li1[s2] = (s2 < c1) ? idxS[r1][s2] : 0;
        }
      }
      #pragma unroll 1
      for (int pair = 0; pair < 2; ++pair) {
        // G <- L * G : per COLUMN (one wave per column), in place.
        for (int c = wv16; c < NN; c += 16) {
          double o0 = 0.0, o1 = 0.0;
          #pragma unroll
          for (int s2 = 0; s2 < 7; ++s2) o0 = fma(lw0[s2], G[li0[s2] * GS + c], o0);
          #pragma unroll
          for (int s2 = 0; s2 < 7; ++s2) o1 = fma(lw1[s2], G[li1[s2] * GS + c], o1);
          asm volatile("s_waitcnt lgkmcnt(0)" ::: "memory");
          G[ln * GS + c] = o0;
          if (h2) G[i2 * GS + c] = o1;
        }
        __syncthreads();
        // G <- G * L^T : per ROW (one wave per row), in place.
        for (int r = wv16; r < NN; r += 16) {
          double o0 = 0.0, o1 = 0.0;
          #pragma unroll
          for (int s2 = 0; s2 < 7; ++s2) o0 = fma(lw0[s2], G[r * GS + li0[s2]], o0);
          #pragma unroll
          for (int s2 = 0; s2 < 7; ++s2) o1 = fma(lw1[s2], G[r * GS + li1[s2]], o1);
          asm volatile("s_waitcnt lgkmcnt(0)" ::: "memory");
          G[r * GS + ln] = o0;
          if (h2) G[r * GS + i2] = o1;
        }
        __syncthreads();
      }
    }

    if (hop == KHOP - 1) {
      // final gram out (f32)
      for (int e = t; e < NN * NN; e += 1024) GfF[e] = (float)G[(e / NN) * GS + (e % NN)];
      __syncthreads();
      // ---- dense L^2 into G (sparse scatter, ascending k order) ----
      if (t < NN) {
        for (int j = 0; j < NN; ++j) G[t * GS + j] = 0.0;
        int cnt = cntS[t];
        for (int s2 = 0; s2 < cnt; ++s2) {
          double w1 = wS[t][s2]; int k = idxS[t][s2];
          int c2 = cntS[k];
          for (int t2 = 0; t2 < c2; ++t2)
            G[t * GS + idxS[k][t2]] += w1 * wS[k][t2];
        }
      }
      __syncthreads();
      // ---- W = build_graph(build_graph(L^2)) ----
      for (int rep = 0; rep < 2; ++rep) {
        if (t < NN) G[t * GS + t] = 0.0;
        __syncthreads();
        if (t < NN) {
          double s = 0.0;
          for (int j = 0; j < NN; ++j) s += G[t * GS + j];
          Dsh[t] = 1.0 / sqrt(s);
        }
        __syncthreads();
        for (int e = t; e < NN * NN; e += 1024) {
          int i = e / NN, j = e % NN;
          G[i * GS + j] = (Dsh[j] * G[i * GS + j]) * Dsh[i];
        }
        __syncthreads();
      }
      // M = I - 0.7*W
      for (int e = t; e < NN * NN; e += 1024) {
        int i = e / NN, j = e % NN;
        G[i * GS + j] = ((i == j) ? 1.0 : 0.0) - 0.7 * G[i * GS + j];
      }
      __syncthreads();
      // ---- Gauss-Jordan sweep inverse in LDS (f64, indices precomputed) ----
      int ii[10], jj[10]; bool vm[10];
      #pragma unroll
      for (int s = 0; s < 10; ++s) {
        int e = t + (s << 10);
        vm[s] = e < NN * NN;
        int ec = vm[s] ? e : 0;
        ii[s] = ec / NN; jj[s] = ec % NN;
      }
      for (int k = 0; k < NN; ++k) {
        if (t < NN) { rowk[t] = G[k * GS + t]; colk[t] = G[t * GS + k]; }
        __syncthreads();
        double pinv = 1.0 / rowk[k];
        #pragma unroll
        for (int s = 0; s < 10; ++s) {
          if (vm[s]) {
            int i = ii[s], j = jj[s];
            double v;
            if (i == k)      v = (j == k) ? pinv : rowk[j] * pinv;
            else if (j == k) v = -(colk[i] * pinv);
            else             v = G[i * GS + j] - colk[i] * (rowk[j] * pinv);
            G[i * GS + j] = v;
          }
        }
        __syncthreads();
      }
      for (int e = t; e < NN * NN; e += 1024) InvF[e] = (float)G[(e / NN) * GS + (e % NN)];
    }
  }
}

// =====================================================================
// Kernel 2: 250 blocks x 512 threads, TWO episodes per block (waves 0-3
// ep A, waves 4-7 ep B). All sinkhorn math in f32 (reference is f32).
// Sinkhorn owner waves: wave 0 (A) and wave 4 (B); barrier payload is
// max over both halves -> identical global lockstep semantics.
// =====================================================================
__global__ __launch_bounds__(512) void k2_epochs(const int* __restrict__ ys,
                                                 const int* __restrict__ yq,
                                                 char* __restrict__ wsb,
                                                 float* __restrict__ out) {
  const int blk = blockIdx.x;
  const int t   = threadIdx.x;
  const int epw = t >> 8;           // half 0/1
  const int tl  = t & 255;
  const int wvl = (t >> 6) & 3;     // wave within half
  const int ln  = t & 63;
  const int b   = blk * 2 + epw;
  const float* Gq   = (const float*)(wsb + CTRL_BYTES) + (size_t)b * EP_FLT;
  const float* Invq = Gq + INV_OFF;
  unsigned* ctrlu = (unsigned*)wsb;

  __shared__ float Z[2][NN * WAYS];
  __shared__ float gvF[2][WAYS * NN];
  __shared__ float pbuf[2][4][WAYS * NN];
  __shared__ float betaS[2][WAYS][NN];
  __shared__ float nrmS[2][NN];
  __shared__ float csv[2][WAYS], pnS[2][WAYS];
  __shared__ int ysS[2][NSUP];
  __shared__ unsigned mS[2];
  __shared__ unsigned Tsh;
  __shared__ int redi[2];

  unsigned rnd = 0;

  if (tl < NSUP) ysS[epw][tl] = ys[b * NSUP + tl];
  if (tl < NN)   nrmS[epw][tl] = Gq[tl * NN + tl];
  for (int e = tl; e < WAYS * NN; e += 256) {
    int w = e / NN, n = e % NN;
    betaS[epw][w][n] = (n >= w * 5 && n < w * 5 + 5) ? 0.2f : 0.0f;
  }
  __syncthreads();

  auto sinkhorn = [&](int base, int n, float cval, bool clamp) {
    const bool own = (wvl == 0);
    const int r0 = ln, r1 = ln + 64;
    const bool h1 = (r1 < n);
    float p0[WAYS], p1[WAYS];
    float up0 = 0.f, up1 = 0.f, u0 = 0.f, u1 = 0.f;
    int aflag = 0;
    int m = 0; int ysq = -1;
    if (own) {
      #pragma unroll
      for (int w = 0; w < WAYS; ++w) {
        p0[w] = Z[epw][(base + r0) * WAYS + w];
        p1[w] = h1 ? Z[epw][(base + r1) * WAYS + w] : 0.f;
      }
      if (clamp && r0 < NSUP) ysq = ysS[epw][r0];
      u0 = p0[0] + p0[1] + p0[2] + p0[3] + p0[4];
      if (h1) u1 = p1[0] + p1[1] + p1[2] + p1[3] + p1[4];
      float dl = fabsf(up0 - u0);
      if (h1) dl = fmaxf(dl, fabsf(up1 - u1));
      aflag = __any(dl > 1e-3f);
    }
    unsigned target = 0;
    for (;;) {
      if (own) {
        while (m < 1000 && ((unsigned)m < target || aflag)) {
          float i0 = frcpf(u0);
          #pragma unroll
          for (int w = 0; w < WAYS; ++w) p0[w] *= i0;
          up0 = u0;
          if (h1) {
            float i1 = frcpf(u1);
            #pragma unroll
            for (int w = 0; w < WAYS; ++w) p1[w] *= i1;
            up1 = u1;
          }
          #pragma unroll
          for (int w = 0; w < WAYS; ++w) {
            float s = wsum64f_fast(p0[w] + (h1 ? p1[w] : 0.f));
            float f = cval * frcpf(s);
            p0[w] *= f;
            if (h1) p1[w] *= f;
          }
          if (clamp && r0 < NSUP) {
            #pragma unroll
            for (int w = 0; w < WAYS; ++w) p0[w] = (ysq == w) ? 1.f : 0.f;
          }
          ++m;
          u0 = p0[0] + p0[1] + p0[2] + p0[3] + p0[4];
          if (h1) u1 = p1[0] + p1[1] + p1[2] + p1[3] + p1[4];
          if ((unsigned)m >= target) {
            float dl = fabsf(up0 - u0);
            if (h1) dl = fmaxf(dl, fabsf(up1 - u1));
            aflag = __any(dl > 1e-3f);
          } else {
            aflag = 1;
          }
        }
        if (ln == 0) mS[epw] = (unsigned)m;
      }
      __syncthreads();
      if (t == 0) {
        unsigned lm = mS[0] > mS[1] ? mS[0] : mS[1];
        Tsh = grid_barrier_max(ctrlu, blk, rnd, lm);
      }
      __syncthreads();
      ++rnd;
      unsigned T = Tsh;
      if (T == target) break;
      target = T;
    }
    if (own) {
      #pragma unroll
      for (int w = 0; w < WAYS; ++w) {
        Z[epw][(base + r0) * WAYS + w] = p0[w];
        if (h1) Z[epw][(base + r1) * WAYS + w] = p1[w];
      }
    }
    __syncthreads();
  };

  for (int epi = 0; epi <= NEPOCH; ++epi) {
    // gv[w][r] = sum_k G[r][k]*beta[w][k]  (k split over 4 waves per half)
    {
      float a0[WAYS], a1[WAYS];
      #pragma unroll
      for (int w = 0; w < WAYS; ++w) { a0[w] = 0.f; a1[w] = 0.f; }
      int k0 = wvl * 25;
      for (int kk = 0; kk < 25; ++kk) {
        int k = k0 + kk;
        float g0 = Gq[(size_t)k * NN + ln];
        float g1 = (ln < NN - 64) ? Gq[(size_t)k * NN + 64 + ln] : 0.f;
        #pragma unroll
        for (int w = 0; w < WAYS; ++w) {
          float bw = betaS[epw][w][k];
          a0[w] = fmaf(g0, bw, a0[w]);
          a1[w] = fmaf(g1, bw, a1[w]);
        }
      }
      #pragma unroll
      for (int w = 0; w < WAYS; ++w) {
        pbuf[epw][wvl][w * NN + ln] = a0[w];
        if (ln < NN - 64) pbuf[epw][wvl][w * NN + 64 + ln] = a1[w];
      }
    }
    __syncthreads();
    for (int e = tl; e < WAYS * NN; e += 256)
      gvF[epw][e] = ((pbuf[epw][0][e] + pbuf[epw][1][e]) + pbuf[epw][2][e]) + pbuf[epw][3][e];
    __syncthreads();
    if (tl < WAYS) {
      float s = 0.f;
      for (int n = 0; n < NN; ++n) s = fmaf(betaS[epw][tl][n], gvF[epw][tl * NN + n], s);
      pnS[epw][tl] = s;
    }
    __syncthreads();
    for (int e = tl; e < NQ * WAYS; e += 256) {
      int r = NSUP + e / WAYS, w = e % WAYS;
      float d = (nrmS[epw][r] + pnS[epw][w]) - 2.0f * gvF[epw][w * NN + r];
      Z[epw][r * WAYS + w] = expf(-10.0f * (d > 0.f ? d : 0.f));
    }
    __syncthreads();
    sinkhorn(NSUP, NQ, 15.0f, false);

    if (epi == NEPOCH) {
      if (tl == 0) redi[epw] = 0;
      __syncthreads();
      if (tl < NQ) {
        int row = NSUP + tl;
        float bv = Z[epw][row * WAYS + 0]; int am = 0;
        #pragma unroll
        for (int w = 1; w < WAYS; ++w) {
          float v = Z[epw][row * WAYS + w];
          if (v > bv) { bv = v; am = w; }
        }
        if (am == yq[b * NQ + tl]) atomicAdd(&redi[epw], 1);
      }
      __syncthreads();
      if (tl == 0) out[b] = (float)redi[epw] / 75.0f;
    } else {
      if (tl < NSUP) {
        #pragma unroll
        for (int w = 0; w < WAYS; ++w) Z[epw][tl * WAYS + w] = (ysS[epw][tl] == w) ? 1.f : 0.f;
      }
      __syncthreads();
      for (int r = wvl; r < NN; r += 4) {
        float a0 = 0, a1 = 0, a2 = 0, a3 = 0, a4 = 0;
        for (int k = ln; k < NN; k += 64) {
          float iv = Invq[(size_t)r * NN + k];
          a0 = fmaf(iv, Z[epw][k * WAYS + 0], a0);
          a1 = fmaf(iv, Z[epw][k * WAYS + 1], a1);
          a2 = fmaf(iv, Z[epw][k * WAYS + 2], a2);
          a3 = fmaf(iv, Z[epw][k * WAYS + 3], a3);
          a4 = fmaf(iv, Z[epw][k * WAYS + 4], a4);
        }
        a0 = wsum64f_fast(a0); a1 = wsum64f_fast(a1); a2 = wsum64f_fast(a2);
        a3 = wsum64f_fast(a3); a4 = wsum64f_fast(a4);
        if (ln == 0) {
          pbuf[epw][0][r * WAYS + 0] = a0; pbuf[epw][0][r * WAYS + 1] = a1;
          pbuf[epw][0][r * WAYS + 2] = a2; pbuf[epw][0][r * WAYS + 3] = a3;
          pbuf[epw][0][r * WAYS + 4] = a4;
        }
      }
      __syncthreads();
      for (int e = tl; e < NN * WAYS; e += 256) Z[epw][e] = pbuf[epw][0][e];
      __syncthreads();
      sinkhorn(0, NN, 20.0f, true);
      if (tl < WAYS) {
        float s = 0.f;
        for (int r = 0; r < NN; ++r) s += Z[epw][r * WAYS + tl];
        csv[epw][tl] = s;
      }
      __syncthreads();
      for (int e = tl; e < NN * WAYS; e += 256) {
        int n = e / WAYS, w = e % WAYS;
        float nb = Z[epw][n * WAYS + w] / csv[epw][w];
        betaS[epw][w][n] = 0.4f * betaS[epw][w][n] + 0.6f * nb;
      }
      __syncthreads();
    }
  }
}

extern "C" void kernel_launch(void* const* d_in, const int* in_sizes, int n_in,
                              void* d_out, int out_size, void* d_ws, size_t ws_size,
                              hipStream_t stream) {
  const float* xs = (const float*)d_in[0];
  const float* xq = (const float*)d_in[1];
  const int*   ys = (const int*)d_in[2];
  const int*   yq = (const int*)d_in[3];
  float* out = (float*)d_out;
  char* ws   = (char*)d_ws;

  hipMemsetAsync(d_ws, 0, CTRL_BYTES, stream);

  (void)hipFuncSetAttribute((const void*)k1_lds,
                            hipFuncAttributeMaxDynamicSharedMemorySize,
                            DYN_LDS_BYTES);
  hipLaunchKernelGGL(k1_lds, dim3(B_RUNS), dim3(1024), DYN_LDS_BYTES, stream, xs, xq, ws);
  hipLaunchKernelGGL(k2_epochs, dim3(KB2), dim3(512), 0, stream, ys, yq, ws, out);
}

// Round 6
// 1734.246 us; speedup vs baseline: 2.5271x; 1.0891x over previous
//
#include <hip/hip_runtime.h>

// ---------------- problem constants ----------------
#define B_RUNS 500
#define WAYS   5
#define NSUP   25
#define NQ     75
#define NN     100
#define DIM    640
#define TOPK   6
#define KHOP   4
#define NEPOCH 10

// ---------------- barrier control region ----------------
#define CTRL_BYTES 262144
#define KB2    250                // k2 blocks (2 episodes each)
#define NBK    25                 // buckets
#define BPB    10                 // blocks per bucket (250/25)
#define NROUND 512
#define READYB 0x80000000u
// ctrl words: barr[25][512] | bmax[25][512] | marr[512] | mmax[512] | bflag[25][512]
// = 77*512 words = 157,696 B <= 256 KB

// per-episode FLOATS: Gf [10000] f32 | Inv [10000] f32
#define EP_FLT   20224
#define GF_OFF   0
#define INV_OFF  10000

// k1 LDS: G (f32, stride 101). Gram staging (2 teams x 1616 f32) is
// OVERLAID on G's region (G is only written after the last chunk).
// 40400 B dynamic + ~8 KB static -> ~49 KB/block -> 2 blocks/CU.
#define GS   101
#define DYN_LDS_BYTES (NN * GS * 4)          // 40400 B

#if defined(__has_builtin)
#if __has_builtin(__builtin_amdgcn_permlane32_swap)
#define HAVE_PLSWAP 1
#endif
#endif

// ---------------- fast wave-64 f32 helpers ----------------
template <int CTRL>
__device__ __forceinline__ float dpp_addf(float v) {
  int r = __builtin_amdgcn_update_dpp(0, __float_as_int(v), CTRL, 0xF, 0xF, false);
  return v + __int_as_float(r);
}
template <int PAT>
__device__ __forceinline__ float swz_addf(float v) {
  return v + __int_as_float(__builtin_amdgcn_ds_swizzle(__float_as_int(v), PAT));
}
__device__ __forceinline__ float swap32_addf(float v) {
#ifdef HAVE_PLSWAP
  int x = __float_as_int(v);
  auto r = __builtin_amdgcn_permlane32_swap(x, x, false, false);
  return __int_as_float(r[0]) + __int_as_float(r[1]);
#else
  return v + __shfl_xor(v, 32, 64);
#endif
}
// full 64-lane f32 sum, result uniform across lanes
__device__ __forceinline__ float wsum64f_fast(float v) {
  v = dpp_addf<0x121>(v);    // row_ror:1
  v = dpp_addf<0x122>(v);    // row_ror:2
  v = dpp_addf<0x124>(v);    // row_ror:4
  v = dpp_addf<0x128>(v);    // row_ror:8
  v = swz_addf<0x401F>(v);   // xor 16
  v = swap32_addf(v);        // xor 32
  return __int_as_float(__builtin_amdgcn_readfirstlane(__float_as_int(v)));
}
// fast f32 reciprocal: hw rcp + 1 Newton
__device__ __forceinline__ float frcpf(float x) {
#if __has_builtin(__builtin_amdgcn_rcpf)
  float r = __builtin_amdgcn_rcpf(x);
#else
  float r = 1.0f / x;
#endif
  float e = fmaf(-x, r, 1.0f);
  r = fmaf(r, e, r);
  return r;
}

// 2-level grid barrier + global max of payload, hierarchical release.
__device__ unsigned grid_barrier_max(unsigned* ctrlu, int b, unsigned rnd, unsigned lm) {
  unsigned r = rnd < (NROUND - 1) ? rnd : (NROUND - 1);
  const int bk = b % NBK;
  unsigned* barr  = ctrlu + bk * NROUND + r;
  unsigned* bmax  = ctrlu + (NBK + bk) * NROUND + r;
  unsigned* marr  = ctrlu + 2 * NBK * NROUND + r;
  unsigned* mmax  = ctrlu + 2 * NBK * NROUND + NROUND + r;
  unsigned* bflag = ctrlu + (2 * NBK + 2) * NROUND + bk * NROUND + r;

  __hip_atomic_fetch_max(bmax, lm, __ATOMIC_RELAXED, __HIP_MEMORY_SCOPE_AGENT);
  unsigned a = __hip_atomic_fetch_add(barr, 1u, __ATOMIC_ACQ_REL, __HIP_MEMORY_SCOPE_AGENT);
  long sp = 0;
  if (a == (unsigned)(BPB - 1)) {
    unsigned bm = __hip_atomic_load(bmax, __ATOMIC_RELAXED, __HIP_MEMORY_SCOPE_AGENT);
    __hip_atomic_fetch_max(mmax, bm, __ATOMIC_RELAXED, __HIP_MEMORY_SCOPE_AGENT);
    __hip_atomic_fetch_add(marr, 1u, __ATOMIC_ACQ_REL, __HIP_MEMORY_SCOPE_AGENT);
    while (__hip_atomic_load(marr, __ATOMIC_RELAXED, __HIP_MEMORY_SCOPE_AGENT) < (unsigned)NBK) {
      __builtin_amdgcn_s_sleep(2);
      if (++sp > 50000000L) break;   // safety: terminate, don't hang
    }
    __builtin_amdgcn_fence(__ATOMIC_ACQUIRE, "agent");
    unsigned g = __hip_atomic_load(mmax, __ATOMIC_RELAXED, __HIP_MEMORY_SCOPE_AGENT);
    __hip_atomic_store(bflag, g | READYB, __ATOMIC_RELEASE, __HIP_MEMORY_SCOPE_AGENT);
    return g;
  } else {
    unsigned f;
    while (!((f = __hip_atomic_load(bflag, __ATOMIC_RELAXED, __HIP_MEMORY_SCOPE_AGENT)) & READYB)) {
      __builtin_amdgcn_s_sleep(4);
      if (++sp > 50000000L) break;   // safety: terminate, don't hang
    }
    __builtin_amdgcn_fence(__ATOMIC_ACQUIRE, "agent");
    return f & ~READYB;
  }
}

// =====================================================================
// Kernel 1 (gram-space), ALL F32 (reference is f32), 1024 threads,
// ~49 KB LDS -> 2 blocks/CU (32 waves) so barrier stalls in one block
// are covered by the other. Gram: 2 teams x 512, 20x25 grid, 5x4 f32
// tile, staging overlaid on G. Per hop: top-6 -> sparse L -> in-place
// LDS congruence. Hop 3: Gf, dense L^2, W chain, M = I-0.7W, GJ
// inverse -> Inv.
// =====================================================================
__global__ __launch_bounds__(1024) void k1_lds(const float* __restrict__ xs,
                                               const float* __restrict__ xq,
                                               char* __restrict__ wsb) {
  extern __shared__ float dynf[];
  float* G   = dynf;                  // 100 x 101 (padded stride)
  float* STf = dynf;                  // staging overlay (gram phase only)

  const int b = blockIdx.x;
  float* GfF  = (float*)(wsb + CTRL_BYTES) + (size_t)b * EP_FLT;
  float* InvF = GfF + INV_OFF;

  __shared__ float nsh[NN], Dsh[NN], rowk[NN], colk[NN];
  __shared__ float wS[NN][7];
  __shared__ int   idxS[NN][7];
  __shared__ int   cntS[NN];

  const int t  = threadIdx.x;
  const int tm = t >> 9;              // team 0/1 (512 threads each)
  const int tt = t & 511;
  const int tx = tt % 25;             // col group 0..24
  const int ty = tt / 25;             // row group 0..20 (>=20 idle)
  const bool act = (ty < 20);
  const int tyc = act ? ty : 19;      // clamped for safe addresses
  float* STt = STf + tm * 1616;

  int ia[5], ja[4];
  #pragma unroll
  for (int a = 0; a < 5; ++a) ia[a] = tyc + 20 * a;   // rows: exact partition
  #pragma unroll
  for (int c = 0; c < 4; ++c) ja[c] = tx + 25 * c;    // cols: exact partition

  // ---- initial gram G0 = F F^T (2-team split-K, f32) ----
  {
    float acc[5][4];
    #pragma unroll
    for (int a = 0; a < 5; ++a)
      #pragma unroll
      for (int c = 0; c < 4; ++c) acc[a][c] = 0.0f;
    const float* xsb = xs + (size_t)b * NSUP * DIM;
    const float* xqb = xq + (size_t)b * NQ * DIM;
    for (int chunk = 0; chunk < 20; ++chunk) {
      int k0 = (chunk * 2 + tm) * 16;
      for (int e = tt; e < NN * 16; e += 512) {
        int r = e >> 4, km = e & 15;
        int k = k0 + km;
        float v = (r < NSUP) ? xsb[r * DIM + k] : xqb[(r - NSUP) * DIM + k];
        STt[(km >> 1) * 202 + 2 * r + (km & 1)] = v;
      }
      __syncthreads();
      #pragma unroll 2
      for (int m = 0; m < 8; ++m) {
        float2 rv[5], cv[4];
        #pragma unroll
        for (int a = 0; a < 5; ++a) rv[a] = *(const float2*)(STt + m * 202 + 2 * ia[a]);
        #pragma unroll
        for (int c = 0; c < 4; ++c) cv[c] = *(const float2*)(STt + m * 202 + 2 * ja[c]);
        #pragma unroll
        for (int a = 0; a < 5; ++a)
          #pragma unroll
          for (int c = 0; c < 4; ++c) {
            acc[a][c] = fmaf(rv[a].x, cv[c].x, acc[a][c]);
            acc[a][c] = fmaf(rv[a].y, cv[c].y, acc[a][c]);
          }
      }
      __syncthreads();
    }
    // staging dead from here; G overlays it
    if (tm == 1 && act) {
      #pragma unroll
      for (int a = 0; a < 5; ++a)
        #pragma unroll
        for (int c = 0; c < 4; ++c)
          G[ia[a] * GS + ja[c]] = acc[a][c];
    }
    __syncthreads();
    if (tm == 0 && act) {
      #pragma unroll
      for (int a = 0; a < 5; ++a)
        #pragma unroll
        for (int c = 0; c < 4; ++c)
          G[ia[a] * GS + ja[c]] = acc[a][c] + G[ia[a] * GS + ja[c]];
    }
    __syncthreads();
  }

  for (int hop = 0; hop < KHOP; ++hop) {
    if (t < NN) nsh[t] = G[t * GS + t];
    __syncthreads();
    // ---- top-6 per row by clamped distance (ascending; ties -> lowest index) ----
    int kj[TOPK]; float ke[TOPK];
    if (t < NN) {
      unsigned long long m0 = 0ull, m1 = 0ull;
      const float nt = nsh[t];
      for (int s = 0; s < TOPK; ++s) {
        float best = 3.0e38f; int bj = 0;
        for (int j = 0; j < NN; ++j) {
          unsigned long long bit = (j < 64) ? ((m0 >> j) & 1ull) : ((m1 >> (j - 64)) & 1ull);
          if (bit) continue;
          float d = (nt + nsh[j]) - 2.0f * G[t * GS + j];
          d = d > 0.0f ? d : 0.0f;
          if (d < best) { best = d; bj = j; }     // strict <: lowest index wins ties
        }
        if (bj < 64) m0 |= 1ull << bj; else m1 |= 1ull << (bj - 64);
      }
      float s = 0.0f;
      unsigned long long mm0 = m0, mm1 = m1;
      #pragma unroll
      for (int sidx = 0; sidx < TOPK; ++sidx) {
        int j;
        if (mm0) { j = __ffsll((long long)mm0) - 1; mm0 &= mm0 - 1; }
        else     { j = 64 + __ffsll((long long)mm1) - 1; mm1 &= mm1 - 1; }
        float d = (nt + nsh[j]) - 2.0f * G[t * GS + j];
        d = d > 0.0f ? d : 0.0f;
        float e = expf(-10.0f * d);
        kj[sidx] = j; ke[sidx] = e;
        s += e;
      }
      Dsh[t] = 1.0f / sqrtf(s);
    }
    __syncthreads();
    // ---- build sparse L row: ascending index, self 0.5 folded/inserted ----
    if (t < NN) {
      int cnt = 0; bool sd = false;
      float dt = Dsh[t];
      #pragma unroll
      for (int sidx = 0; sidx < TOPK; ++sidx) {
        int j = kj[sidx];
        float lw = 0.5f * ((Dsh[j] * ke[sidx]) * dt);
        if (j == t) { lw = 0.5f + lw; sd = true; }
        else if (!sd && j > t) { idxS[t][cnt] = t; wS[t][cnt] = 0.5f; ++cnt; sd = true; }
        idxS[t][cnt] = j; wS[t][cnt] = lw; ++cnt;
      }
      if (!sd) { idxS[t][cnt] = t; wS[t][cnt] = 0.5f; ++cnt; }
      cntS[t] = cnt;
    }
    __syncthreads();

    // ---- congruence: G <- L (L G L^T) L^T, fully in-place in LDS ----
    {
      const int wv16 = t >> 6, ln = t & 63;
      const int i2 = ln + 64;
      const bool h2 = (i2 < NN);
      const int r1 = h2 ? i2 : 0;
      float lw0[7], lw1[7]; int li0[7], li1[7];
      {
        int c0 = cntS[ln];
        int c1 = h2 ? cntS[r1] : 0;
        #pragma unroll
        for (int s2 = 0; s2 < 7; ++s2) {
          lw0[s2] = (s2 < c0) ? wS[ln][s2] : 0.0f;
          li0[s2] = (s2 < c0) ? idxS[ln][s2] : 0;
          lw1[s2] = (s2 < c1) ? wS[r1][s2] : 0.0f;
          li1[s2] = (s2 < c1) ? idxS[r1][s2] : 0;
        }
      }
      #pragma unroll 1
      for (int pair = 0; pair < 2; ++pair) {
        // G <- L * G : per COLUMN (one wave per column), in place.
        for (int c = wv16; c < NN; c += 16) {
          float o0 = 0.0f, o1 = 0.0f;
          #pragma unroll
          for (int s2 = 0; s2 < 7; ++s2) o0 = fmaf(lw0[s2], G[li0[s2] * GS + c], o0);
          #pragma unroll
          for (int s2 = 0; s2 < 7; ++s2) o1 = fmaf(lw1[s2], G[li1[s2] * GS + c], o1);
          asm volatile("s_waitcnt lgkmcnt(0)" ::: "memory");
          G[ln * GS + c] = o0;
          if (h2) G[i2 * GS + c] = o1;
        }
        __syncthreads();
        // G <- G * L^T : per ROW (one wave per row), in place.
        for (int r = wv16; r < NN; r += 16) {
          float o0 = 0.0f, o1 = 0.0f;
          #pragma unroll
          for (int s2 = 0; s2 < 7; ++s2) o0 = fmaf(lw0[s2], G[r * GS + li0[s2]], o0);
          #pragma unroll
          for (int s2 = 0; s2 < 7; ++s2) o1 = fmaf(lw1[s2], G[r * GS + li1[s2]], o1);
          asm volatile("s_waitcnt lgkmcnt(0)" ::: "memory");
          G[r * GS + ln] = o0;
          if (h2) G[r * GS + i2] = o1;
        }
        __syncthreads();
      }
    }

    if (hop == KHOP - 1) {
      // final gram out
      for (int e = t; e < NN * NN; e += 1024) GfF[e] = G[(e / NN) * GS + (e % NN)];
      __syncthreads();
      // ---- dense L^2 into G (sparse scatter, ascending k order) ----
      if (t < NN) {
        for (int j = 0; j < NN; ++j) G[t * GS + j] = 0.0f;
        int cnt = cntS[t];
        for (int s2 = 0; s2 < cnt; ++s2) {
          float w1 = wS[t][s2]; int k = idxS[t][s2];
          int c2 = cntS[k];
          for (int t2 = 0; t2 < c2; ++t2)
            G[t * GS + idxS[k][t2]] += w1 * wS[k][t2];
        }
      }
      __syncthreads();
      // ---- W = build_graph(build_graph(L^2)) ----
      for (int rep = 0; rep < 2; ++rep) {
        if (t < NN) G[t * GS + t] = 0.0f;
        __syncthreads();
        if (t < NN) {
          float s = 0.0f;
          for (int j = 0; j < NN; ++j) s += G[t * GS + j];
          Dsh[t] = 1.0f / sqrtf(s);
        }
        __syncthreads();
        for (int e = t; e < NN * NN; e += 1024) {
          int i = e / NN, j = e % NN;
          G[i * GS + j] = (Dsh[j] * G[i * GS + j]) * Dsh[i];
        }
        __syncthreads();
      }
      // M = I - 0.7*W
      for (int e = t; e < NN * NN; e += 1024) {
        int i = e / NN, j = e % NN;
        G[i * GS + j] = ((i == j) ? 1.0f : 0.0f) - 0.7f * G[i * GS + j];
      }
      __syncthreads();
      // ---- Gauss-Jordan sweep inverse in LDS (indices precomputed) ----
      int ii[10], jj[10]; bool vm[10];
      #pragma unroll
      for (int s = 0; s < 10; ++s) {
        int e = t + (s << 10);
        vm[s] = e < NN * NN;
        int ec = vm[s] ? e : 0;
        ii[s] = ec / NN; jj[s] = ec % NN;
      }
      for (int k = 0; k < NN; ++k) {
        if (t < NN) { rowk[t] = G[k * GS + t]; colk[t] = G[t * GS + k]; }
        __syncthreads();
        float pinv = 1.0f / rowk[k];
        #pragma unroll
        for (int s = 0; s < 10; ++s) {
          if (vm[s]) {
            int i = ii[s], j = jj[s];
            float v;
            if (i == k)      v = (j == k) ? pinv : rowk[j] * pinv;
            else if (j == k) v = -(colk[i] * pinv);
            else             v = G[i * GS + j] - colk[i] * (rowk[j] * pinv);
            G[i * GS + j] = v;
          }
        }
        __syncthreads();
      }
      for (int e = t; e < NN * NN; e += 1024) InvF[e] = G[(e / NN) * GS + (e % NN)];
    }
  }
}

// =====================================================================
// Kernel 2: 250 blocks x 512 threads, TWO episodes per block (waves 0-3
// ep A, waves 4-7 ep B). All sinkhorn math in f32. Unchanged from R5.
// =====================================================================
__global__ __launch_bounds__(512) void k2_epochs(const int* __restrict__ ys,
                                                 const int* __restrict__ yq,
                                                 char* __restrict__ wsb,
                                                 float* __restrict__ out) {
  const int blk = blockIdx.x;
  const int t   = threadIdx.x;
  const int epw = t >> 8;           // half 0/1
  const int tl  = t & 255;
  const int wvl = (t >> 6) & 3;     // wave within half
  const int ln  = t & 63;
  const int b   = blk * 2 + epw;
  const float* Gq   = (const float*)(wsb + CTRL_BYTES) + (size_t)b * EP_FLT;
  const float* Invq = Gq + INV_OFF;
  unsigned* ctrlu = (unsigned*)wsb;

  __shared__ float Z[2][NN * WAYS];
  __shared__ float gvF[2][WAYS * NN];
  __shared__ float pbuf[2][4][WAYS * NN];
  __shared__ float betaS[2][WAYS][NN];
  __shared__ float nrmS[2][NN];
  __shared__ float csv[2][WAYS], pnS[2][WAYS];
  __shared__ int ysS[2][NSUP];
  __shared__ unsigned mS[2];
  __shared__ unsigned Tsh;
  __shared__ int redi[2];

  unsigned rnd = 0;

  if (tl < NSUP) ysS[epw][tl] = ys[b * NSUP + tl];
  if (tl < NN)   nrmS[epw][tl] = Gq[tl * NN + tl];
  for (int e = tl; e < WAYS * NN; e += 256) {
    int w = e / NN, n = e % NN;
    betaS[epw][w][n] = (n >= w * 5 && n < w * 5 + 5) ? 0.2f : 0.0f;
  }
  __syncthreads();

  auto sinkhorn = [&](int base, int n, float cval, bool clamp) {
    const bool own = (wvl == 0);
    const int r0 = ln, r1 = ln + 64;
    const bool h1 = (r1 < n);
    float p0[WAYS], p1[WAYS];
    float up0 = 0.f, up1 = 0.f, u0 = 0.f, u1 = 0.f;
    int aflag = 0;
    int m = 0; int ysq = -1;
    if (own) {
      #pragma unroll
      for (int w = 0; w < WAYS; ++w) {
        p0[w] = Z[epw][(base + r0) * WAYS + w];
        p1[w] = h1 ? Z[epw][(base + r1) * WAYS + w] : 0.f;
      }
      if (clamp && r0 < NSUP) ysq = ysS[epw][r0];
      u0 = p0[0] + p0[1] + p0[2] + p0[3] + p0[4];
      if (h1) u1 = p1[0] + p1[1] + p1[2] + p1[3] + p1[4];
      float dl = fabsf(up0 - u0);
      if (h1) dl = fmaxf(dl, fabsf(up1 - u1));
      aflag = __any(dl > 1e-3f);
    }
    unsigned target = 0;
    for (;;) {
      if (own) {
        while (m < 1000 && ((unsigned)m < target || aflag)) {
          float i0 = frcpf(u0);
          #pragma unroll
          for (int w = 0; w < WAYS; ++w) p0[w] *= i0;
          up0 = u0;
          if (h1) {
            float i1 = frcpf(u1);
            #pragma unroll
            for (int w = 0; w < WAYS; ++w) p1[w] *= i1;
            up1 = u1;
          }
          #pragma unroll
          for (int w = 0; w < WAYS; ++w) {
            float s = wsum64f_fast(p0[w] + (h1 ? p1[w] : 0.f));
            float f = cval * frcpf(s);
            p0[w] *= f;
            if (h1) p1[w] *= f;
          }
          if (clamp && r0 < NSUP) {
            #pragma unroll
            for (int w = 0; w < WAYS; ++w) p0[w] = (ysq == w) ? 1.f : 0.f;
          }
          ++m;
          u0 = p0[0] + p0[1] + p0[2] + p0[3] + p0[4];
          if (h1) u1 = p1[0] + p1[1] + p1[2] + p1[3] + p1[4];
          if ((unsigned)m >= target) {
            float dl = fabsf(up0 - u0);
            if (h1) dl = fmaxf(dl, fabsf(up1 - u1));
            aflag = __any(dl > 1e-3f);
          } else {
            aflag = 1;
          }
        }
        if (ln == 0) mS[epw] = (unsigned)m;
      }
      __syncthreads();
      if (t == 0) {
        unsigned lm = mS[0] > mS[1] ? mS[0] : mS[1];
        Tsh = grid_barrier_max(ctrlu, blk, rnd, lm);
      }
      __syncthreads();
      ++rnd;
      unsigned T = Tsh;
      if (T == target) break;
      target = T;
    }
    if (own) {
      #pragma unroll
      for (int w = 0; w < WAYS; ++w) {
        Z[epw][(base + r0) * WAYS + w] = p0[w];
        if (h1) Z[epw][(base + r1) * WAYS + w] = p1[w];
      }
    }
    __syncthreads();
  };

  for (int epi = 0; epi <= NEPOCH; ++epi) {
    // gv[w][r] = sum_k G[r][k]*beta[w][k]  (k split over 4 waves per half)
    {
      float a0[WAYS], a1[WAYS];
      #pragma unroll
      for (int w = 0; w < WAYS; ++w) { a0[w] = 0.f; a1[w] = 0.f; }
      int k0 = wvl * 25;
      for (int kk = 0; kk < 25; ++kk) {
        int k = k0 + kk;
        float g0 = Gq[(size_t)k * NN + ln];
        float g1 = (ln < NN - 64) ? Gq[(size_t)k * NN + 64 + ln] : 0.f;
        #pragma unroll
        for (int w = 0; w < WAYS; ++w) {
          float bw = betaS[epw][w][k];
          a0[w] = fmaf(g0, bw, a0[w]);
          a1[w] = fmaf(g1, bw, a1[w]);
        }
      }
      #pragma unroll
      for (int w = 0; w < WAYS; ++w) {
        pbuf[epw][wvl][w * NN + ln] = a0[w];
        if (ln < NN - 64) pbuf[epw][wvl][w * NN + 64 + ln] = a1[w];
      }
    }
    __syncthreads();
    for (int e = tl; e < WAYS * NN; e += 256)
      gvF[epw][e] = ((pbuf[epw][0][e] + pbuf[epw][1][e]) + pbuf[epw][2][e]) + pbuf[epw][3][e];
    __syncthreads();
    if (tl < WAYS) {
      float s = 0.f;
      for (int n = 0; n < NN; ++n) s = fmaf(betaS[epw][tl][n], gvF[epw][tl * NN + n], s);
      pnS[epw][tl] = s;
    }
    __syncthreads();
    for (int e = tl; e < NQ * WAYS; e += 256) {
      int r = NSUP + e / WAYS, w = e % WAYS;
      float d = (nrmS[epw][r] + pnS[epw][w]) - 2.0f * gvF[epw][w * NN + r];
      Z[epw][r * WAYS + w] = expf(-10.0f * (d > 0.f ? d : 0.f));
    }
    __syncthreads();
    sinkhorn(NSUP, NQ, 15.0f, false);

    if (epi == NEPOCH) {
      if (tl == 0) redi[epw] = 0;
      __syncthreads();
      if (tl < NQ) {
        int row = NSUP + tl;
        float bv = Z[epw][row * WAYS + 0]; int am = 0;
        #pragma unroll
        for (int w = 1; w < WAYS; ++w) {
          float v = Z[epw][row * WAYS + w];
          if (v > bv) { bv = v; am = w; }
        }
        if (am == yq[b * NQ + tl]) atomicAdd(&redi[epw], 1);
      }
      __syncthreads();
      if (tl == 0) out[b] = (float)redi[epw] / 75.0f;
    } else {
      if (tl < NSUP) {
        #pragma unroll
        for (int w = 0; w < WAYS; ++w) Z[epw][tl * WAYS + w] = (ysS[epw][tl] == w) ? 1.f : 0.f;
      }
      __syncthreads();
      for (int r = wvl; r < NN; r += 4) {
        float a0 = 0, a1 = 0, a2 = 0, a3 = 0, a4 = 0;
        for (int k = ln; k < NN; k += 64) {
          float iv = Invq[(size_t)r * NN + k];
          a0 = fmaf(iv, Z[epw][k * WAYS + 0], a0);
          a1 = fmaf(iv, Z[epw][k * WAYS + 1], a1);
          a2 = fmaf(iv, Z[epw][k * WAYS + 2], a2);
          a3 = fmaf(iv, Z[epw][k * WAYS + 3], a3);
          a4 = fmaf(iv, Z[epw][k * WAYS + 4], a4);
        }
        a0 = wsum64f_fast(a0); a1 = wsum64f_fast(a1); a2 = wsum64f_fast(a2);
        a3 = wsum64f_fast(a3); a4 = wsum64f_fast(a4);
        if (ln == 0) {
          pbuf[epw][0][r * WAYS + 0] = a0; pbuf[epw][0][r * WAYS + 1] = a1;
          pbuf[epw][0][r * WAYS + 2] = a2; pbuf[epw][0][r * WAYS + 3] = a3;
          pbuf[epw][0][r * WAYS + 4] = a4;
        }
      }
      __syncthreads();
      for (int e = tl; e < NN * WAYS; e += 256) Z[epw][e] = pbuf[epw][0][e];
      __syncthreads();
      sinkhorn(0, NN, 20.0f, true);
      if (tl < WAYS) {
        float s = 0.f;
        for (int r = 0; r < NN; ++r) s += Z[epw][r * WAYS + tl];
        csv[epw][tl] = s;
      }
      __syncthreads();
      for (int e = tl; e < NN * WAYS; e += 256) {
        int n = e / WAYS, w = e % WAYS;
        float nb = Z[epw][n * WAYS + w] / csv[epw][w];
        betaS[epw][w][n] = 0.4f * betaS[epw][w][n] + 0.6f * nb;
      }
      __syncthreads();
    }
  }
}

extern "C" void kernel_launch(void* const* d_in, const int* in_sizes, int n_in,
                              void* d_out, int out_size, void* d_ws, size_t ws_size,
                              hipStream_t stream) {
  const float* xs = (const float*)d_in[0];
  const float* xq = (const float*)d_in[1];
  const int*   ys = (const int*)d_in[2];
  const int*   yq = (const int*)d_in[3];
  float* out = (float*)d_out;
  char* ws   = (char*)d_ws;

  hipMemsetAsync(d_ws, 0, CTRL_BYTES, stream);

  (void)hipFuncSetAttribute((const void*)k1_lds,
                            hipFuncAttributeMaxDynamicSharedMemorySize,
                            DYN_LDS_BYTES);
  hipLaunchKernelGGL(k1_lds, dim3(B_RUNS), dim3(1024), DYN_LDS_BYTES, stream, xs, xq, ws);
  hipLaunchKernelGGL(k2_epochs, dim3(KB2), dim3(512), 0, stream, ys, yq, ws, out);
}

// Round 7
// 1585.359 us; speedup vs baseline: 2.7644x; 1.0939x over previous
//
#include <hip/hip_runtime.h>

// ---------------- problem constants ----------------
#define B_RUNS 500
#define WAYS   5
#define NSUP   25
#define NQ     75
#define NN     100
#define DIM    640
#define TOPK   6
#define KHOP   4
#define NEPOCH 10

// ---------------- barrier control region ----------------
#define CTRL_BYTES 262144
#define KB2    250                // k2 blocks (2 episodes each)
#define NBK    25                 // buckets
#define BPB    10                 // blocks per bucket (250/25)
#define NROUND 512
#define READYB 0x80000000u
// ctrl words: barr[25][512] | bmax[25][512] | marr[512] | mmax[512] | bflag[25][512]
// = 77*512 words = 157,696 B <= 256 KB

// per-episode FLOATS: Gf [10000] f32 | Inv [10000] f32
#define EP_FLT   20224
#define GF_OFF   0
#define INV_OFF  10000

// k1 LDS: G (f32, stride 101), staging overlaid. ~48 KB total with
// statics -> 3 blocks/CU (24 waves) for stall coverage.
#define GS   101
#define DYN_LDS_BYTES (NN * GS * 4)          // 40400 B

#if defined(__has_builtin)
#if __has_builtin(__builtin_amdgcn_permlane32_swap)
#define HAVE_PLSWAP 1
#endif
#endif

// ---------------- fast wave-64 f32 helpers ----------------
template <int CTRL>
__device__ __forceinline__ float dpp_addf(float v) {
  int r = __builtin_amdgcn_update_dpp(0, __float_as_int(v), CTRL, 0xF, 0xF, false);
  return v + __int_as_float(r);
}
template <int PAT>
__device__ __forceinline__ float swz_addf(float v) {
  return v + __int_as_float(__builtin_amdgcn_ds_swizzle(__float_as_int(v), PAT));
}
__device__ __forceinline__ float swap32_addf(float v) {
#ifdef HAVE_PLSWAP
  int x = __float_as_int(v);
  auto r = __builtin_amdgcn_permlane32_swap(x, x, false, false);
  return __int_as_float(r[0]) + __int_as_float(r[1]);
#else
  return v + __shfl_xor(v, 32, 64);
#endif
}
// full 64-lane f32 sum, result uniform across lanes
__device__ __forceinline__ float wsum64f_fast(float v) {
  v = dpp_addf<0x121>(v);    // row_ror:1
  v = dpp_addf<0x122>(v);    // row_ror:2
  v = dpp_addf<0x124>(v);    // row_ror:4
  v = dpp_addf<0x128>(v);    // row_ror:8
  v = swz_addf<0x401F>(v);   // xor 16
  v = swap32_addf(v);        // xor 32
  return __int_as_float(__builtin_amdgcn_readfirstlane(__float_as_int(v)));
}
// fast f32 reciprocal: hw rcp + 1 Newton
__device__ __forceinline__ float frcpf(float x) {
#if __has_builtin(__builtin_amdgcn_rcpf)
  float r = __builtin_amdgcn_rcpf(x);
#else
  float r = 1.0f / x;
#endif
  float e = fmaf(-x, r, 1.0f);
  r = fmaf(r, e, r);
  return r;
}

// 2-level grid barrier + global max of payload, hierarchical release.
__device__ unsigned grid_barrier_max(unsigned* ctrlu, int b, unsigned rnd, unsigned lm) {
  unsigned r = rnd < (NROUND - 1) ? rnd : (NROUND - 1);
  const int bk = b % NBK;
  unsigned* barr  = ctrlu + bk * NROUND + r;
  unsigned* bmax  = ctrlu + (NBK + bk) * NROUND + r;
  unsigned* marr  = ctrlu + 2 * NBK * NROUND + r;
  unsigned* mmax  = ctrlu + 2 * NBK * NROUND + NROUND + r;
  unsigned* bflag = ctrlu + (2 * NBK + 2) * NROUND + bk * NROUND + r;

  __hip_atomic_fetch_max(bmax, lm, __ATOMIC_RELAXED, __HIP_MEMORY_SCOPE_AGENT);
  unsigned a = __hip_atomic_fetch_add(barr, 1u, __ATOMIC_ACQ_REL, __HIP_MEMORY_SCOPE_AGENT);
  long sp = 0;
  if (a == (unsigned)(BPB - 1)) {
    unsigned bm = __hip_atomic_load(bmax, __ATOMIC_RELAXED, __HIP_MEMORY_SCOPE_AGENT);
    __hip_atomic_fetch_max(mmax, bm, __ATOMIC_RELAXED, __HIP_MEMORY_SCOPE_AGENT);
    __hip_atomic_fetch_add(marr, 1u, __ATOMIC_ACQ_REL, __HIP_MEMORY_SCOPE_AGENT);
    while (__hip_atomic_load(marr, __ATOMIC_RELAXED, __HIP_MEMORY_SCOPE_AGENT) < (unsigned)NBK) {
      __builtin_amdgcn_s_sleep(2);
      if (++sp > 50000000L) break;   // safety: terminate, don't hang
    }
    __builtin_amdgcn_fence(__ATOMIC_ACQUIRE, "agent");
    unsigned g = __hip_atomic_load(mmax, __ATOMIC_RELAXED, __HIP_MEMORY_SCOPE_AGENT);
    __hip_atomic_store(bflag, g | READYB, __ATOMIC_RELEASE, __HIP_MEMORY_SCOPE_AGENT);
    return g;
  } else {
    unsigned f;
    while (!((f = __hip_atomic_load(bflag, __ATOMIC_RELAXED, __HIP_MEMORY_SCOPE_AGENT)) & READYB)) {
      __builtin_amdgcn_s_sleep(4);
      if (++sp > 50000000L) break;   // safety: terminate, don't hang
    }
    __builtin_amdgcn_fence(__ATOMIC_ACQUIRE, "agent");
    return f & ~READYB;
  }
}

// =====================================================================
// Kernel 1 (gram-space), f32, 512 threads (8 waves) x ~48 KB LDS ->
// 3 blocks/CU: independent barrier domains cover each other's stalls.
// Gram: single team, 16x32 grid, 7x4 tile, 40 K-chunks, staging
// overlaid on G. Per hop: top-6 -> sparse L -> in-place congruence
// (8-wave stride). Hop 3: Gf, dense L^2, W chain, M = I-0.7W, GJ -> Inv.
// =====================================================================
__global__ __launch_bounds__(512, 6) void k1_lds(const float* __restrict__ xs,
                                                 const float* __restrict__ xq,
                                                 char* __restrict__ wsb) {
  extern __shared__ float dynf[];
  float* G   = dynf;                  // 100 x 101 (padded stride)
  float* STf = dynf;                  // staging overlay (gram phase only)

  const int b = blockIdx.x;
  float* GfF  = (float*)(wsb + CTRL_BYTES) + (size_t)b * EP_FLT;
  float* InvF = GfF + INV_OFF;

  __shared__ float nsh[NN], Dsh[NN], rowk[NN], colk[NN];
  __shared__ float wS[NN][7];
  __shared__ int   idxS[NN][7];
  __shared__ int   cntS[NN];

  const int t  = threadIdx.x;

  // ---- initial gram G0 = F F^T (single team, 16x32 grid, 7x4 tile) ----
  {
    const int tx = t & 31;            // col group 0..31
    const int ty = t >> 5;            // row group 0..15
    int ia[7], ja[4];
    #pragma unroll
    for (int a = 0; a < 7; ++a) { int v = ty + 16 * a; ia[a] = v < NN ? v : NN - 1; }
    #pragma unroll
    for (int c = 0; c < 4; ++c) { int v = tx + 32 * c; ja[c] = v < NN ? v : NN - 1; }

    float acc[7][4];
    #pragma unroll
    for (int a = 0; a < 7; ++a)
      #pragma unroll
      for (int c = 0; c < 4; ++c) acc[a][c] = 0.0f;
    const float* xsb = xs + (size_t)b * NSUP * DIM;
    const float* xqb = xq + (size_t)b * NQ * DIM;
    for (int chunk = 0; chunk < 40; ++chunk) {
      int k0 = chunk * 16;
      for (int e = t; e < NN * 16; e += 512) {
        int r = e >> 4, km = e & 15;
        int k = k0 + km;
        float v = (r < NSUP) ? xsb[r * DIM + k] : xqb[(r - NSUP) * DIM + k];
        STf[(km >> 1) * 202 + 2 * r + (km & 1)] = v;
      }
      __syncthreads();
      #pragma unroll 2
      for (int m = 0; m < 8; ++m) {
        float2 rv[7], cv[4];
        #pragma unroll
        for (int a = 0; a < 7; ++a) rv[a] = *(const float2*)(STf + m * 202 + 2 * ia[a]);
        #pragma unroll
        for (int c = 0; c < 4; ++c) cv[c] = *(const float2*)(STf + m * 202 + 2 * ja[c]);
        #pragma unroll
        for (int a = 0; a < 7; ++a)
          #pragma unroll
          for (int c = 0; c < 4; ++c) {
            acc[a][c] = fmaf(rv[a].x, cv[c].x, acc[a][c]);
            acc[a][c] = fmaf(rv[a].y, cv[c].y, acc[a][c]);
          }
      }
      __syncthreads();
    }
    // staging dead from here; G overlays it
    #pragma unroll
    for (int a = 0; a < 7; ++a)
      #pragma unroll
      for (int c = 0; c < 4; ++c) {
        int i = ty + 16 * a, j = tx + 32 * c;
        if (i < NN && j < NN) G[i * GS + j] = acc[a][c];
      }
    __syncthreads();
  }

  for (int hop = 0; hop < KHOP; ++hop) {
    if (t < NN) nsh[t] = G[t * GS + t];
    __syncthreads();
    // ---- top-6 per row by clamped distance (ascending; ties -> lowest index) ----
    int kj[TOPK]; float ke[TOPK];
    if (t < NN) {
      unsigned long long m0 = 0ull, m1 = 0ull;
      const float nt = nsh[t];
      for (int s = 0; s < TOPK; ++s) {
        float best = 3.0e38f; int bj = 0;
        for (int j = 0; j < NN; ++j) {
          unsigned long long bit = (j < 64) ? ((m0 >> j) & 1ull) : ((m1 >> (j - 64)) & 1ull);
          if (bit) continue;
          float d = (nt + nsh[j]) - 2.0f * G[t * GS + j];
          d = d > 0.0f ? d : 0.0f;
          if (d < best) { best = d; bj = j; }     // strict <: lowest index wins ties
        }
        if (bj < 64) m0 |= 1ull << bj; else m1 |= 1ull << (bj - 64);
      }
      float s = 0.0f;
      unsigned long long mm0 = m0, mm1 = m1;
      #pragma unroll
      for (int sidx = 0; sidx < TOPK; ++sidx) {
        int j;
        if (mm0) { j = __ffsll((long long)mm0) - 1; mm0 &= mm0 - 1; }
        else     { j = 64 + __ffsll((long long)mm1) - 1; mm1 &= mm1 - 1; }
        float d = (nt + nsh[j]) - 2.0f * G[t * GS + j];
        d = d > 0.0f ? d : 0.0f;
        float e = expf(-10.0f * d);
        kj[sidx] = j; ke[sidx] = e;
        s += e;
      }
      Dsh[t] = 1.0f / sqrtf(s);
    }
    __syncthreads();
    // ---- build sparse L row: ascending index, self 0.5 folded/inserted ----
    if (t < NN) {
      int cnt = 0; bool sd = false;
      float dt = Dsh[t];
      #pragma unroll
      for (int sidx = 0; sidx < TOPK; ++sidx) {
        int j = kj[sidx];
        float lw = 0.5f * ((Dsh[j] * ke[sidx]) * dt);
        if (j == t) { lw = 0.5f + lw; sd = true; }
        else if (!sd && j > t) { idxS[t][cnt] = t; wS[t][cnt] = 0.5f; ++cnt; sd = true; }
        idxS[t][cnt] = j; wS[t][cnt] = lw; ++cnt;
      }
      if (!sd) { idxS[t][cnt] = t; wS[t][cnt] = 0.5f; ++cnt; }
      cntS[t] = cnt;
    }
    __syncthreads();

    // ---- congruence: G <- L (L G L^T) L^T, fully in-place in LDS ----
    {
      const int wv8 = t >> 6, ln = t & 63;
      const int i2 = ln + 64;
      const bool h2 = (i2 < NN);
      const int r1 = h2 ? i2 : 0;
      float lw0[7], lw1[7]; int li0[7], li1[7];
      {
        int c0 = cntS[ln];
        int c1 = h2 ? cntS[r1] : 0;
        #pragma unroll
        for (int s2 = 0; s2 < 7; ++s2) {
          lw0[s2] = (s2 < c0) ? wS[ln][s2] : 0.0f;
          li0[s2] = (s2 < c0) ? idxS[ln][s2] : 0;
          lw1[s2] = (s2 < c1) ? wS[r1][s2] : 0.0f;
          li1[s2] = (s2 < c1) ? idxS[r1][s2] : 0;
        }
      }
      #pragma unroll 1
      for (int pair = 0; pair < 2; ++pair) {
        // G <- L * G : per COLUMN (one wave per column), in place.
        for (int c = wv8; c < NN; c += 8) {
          float o0 = 0.0f, o1 = 0.0f;
          #pragma unroll
          for (int s2 = 0; s2 < 7; ++s2) o0 = fmaf(lw0[s2], G[li0[s2] * GS + c], o0);
          #pragma unroll
          for (int s2 = 0; s2 < 7; ++s2) o1 = fmaf(lw1[s2], G[li1[s2] * GS + c], o1);
          asm volatile("s_waitcnt lgkmcnt(0)" ::: "memory");
          G[ln * GS + c] = o0;
          if (h2) G[i2 * GS + c] = o1;
        }
        __syncthreads();
        // G <- G * L^T : per ROW (one wave per row), in place.
        for (int r = wv8; r < NN; r += 8) {
          float o0 = 0.0f, o1 = 0.0f;
          #pragma unroll
          for (int s2 = 0; s2 < 7; ++s2) o0 = fmaf(lw0[s2], G[r * GS + li0[s2]], o0);
          #pragma unroll
          for (int s2 = 0; s2 < 7; ++s2) o1 = fmaf(lw1[s2], G[r * GS + li1[s2]], o1);
          asm volatile("s_waitcnt lgkmcnt(0)" ::: "memory");
          G[r * GS + ln] = o0;
          if (h2) G[r * GS + i2] = o1;
        }
        __syncthreads();
      }
    }

    if (hop == KHOP - 1) {
      // final gram out
      for (int e = t; e < NN * NN; e += 512) GfF[e] = G[(e / NN) * GS + (e % NN)];
      __syncthreads();
      // ---- dense L^2 into G (sparse scatter, ascending k order) ----
      if (t < NN) {
        for (int j = 0; j < NN; ++j) G[t * GS + j] = 0.0f;
        int cnt = cntS[t];
        for (int s2 = 0; s2 < cnt; ++s2) {
          float w1 = wS[t][s2]; int k = idxS[t][s2];
          int c2 = cntS[k];
          for (int t2 = 0; t2 < c2; ++t2)
            G[t * GS + idxS[k][t2]] += w1 * wS[k][t2];
        }
      }
      __syncthreads();
      // ---- W = build_graph(build_graph(L^2)) ----
      for (int rep = 0; rep < 2; ++rep) {
        if (t < NN) G[t * GS + t] = 0.0f;
        __syncthreads();
        if (t < NN) {
          float s = 0.0f;
          for (int j = 0; j < NN; ++j) s += G[t * GS + j];
          Dsh[t] = 1.0f / sqrtf(s);
        }
        __syncthreads();
        for (int e = t; e < NN * NN; e += 512) {
          int i = e / NN, j = e % NN;
          G[i * GS + j] = (Dsh[j] * G[i * GS + j]) * Dsh[i];
        }
        __syncthreads();
      }
      // M = I - 0.7*W
      for (int e = t; e < NN * NN; e += 512) {
        int i = e / NN, j = e % NN;
        G[i * GS + j] = ((i == j) ? 1.0f : 0.0f) - 0.7f * G[i * GS + j];
      }
      __syncthreads();
      // ---- Gauss-Jordan sweep inverse in LDS ----
      for (int k = 0; k < NN; ++k) {
        if (t < NN) { rowk[t] = G[k * GS + t]; colk[t] = G[t * GS + k]; }
        __syncthreads();
        float pinv = 1.0f / rowk[k];
        for (int e = t; e < NN * NN; e += 512) {
          int i = e / NN, j = e % NN;
          float v;
          if (i == k)      v = (j == k) ? pinv : rowk[j] * pinv;
          else if (j == k) v = -(colk[i] * pinv);
          else             v = G[i * GS + j] - colk[i] * (rowk[j] * pinv);
          G[i * GS + j] = v;
        }
        __syncthreads();
      }
      for (int e = t; e < NN * NN; e += 512) InvF[e] = G[(e / NN) * GS + (e % NN)];
    }
  }
}

// =====================================================================
// Kernel 2: 250 blocks x 512 threads, TWO episodes per block (waves 0-3
// ep A, waves 4-7 ep B). All sinkhorn math in f32. Unchanged from R6.
// =====================================================================
__global__ __launch_bounds__(512) void k2_epochs(const int* __restrict__ ys,
                                                 const int* __restrict__ yq,
                                                 char* __restrict__ wsb,
                                                 float* __restrict__ out) {
  const int blk = blockIdx.x;
  const int t   = threadIdx.x;
  const int epw = t >> 8;           // half 0/1
  const int tl  = t & 255;
  const int wvl = (t >> 6) & 3;     // wave within half
  const int ln  = t & 63;
  const int b   = blk * 2 + epw;
  const float* Gq   = (const float*)(wsb + CTRL_BYTES) + (size_t)b * EP_FLT;
  const float* Invq = Gq + INV_OFF;
  unsigned* ctrlu = (unsigned*)wsb;

  __shared__ float Z[2][NN * WAYS];
  __shared__ float gvF[2][WAYS * NN];
  __shared__ float pbuf[2][4][WAYS * NN];
  __shared__ float betaS[2][WAYS][NN];
  __shared__ float nrmS[2][NN];
  __shared__ float csv[2][WAYS], pnS[2][WAYS];
  __shared__ int ysS[2][NSUP];
  __shared__ unsigned mS[2];
  __shared__ unsigned Tsh;
  __shared__ int redi[2];

  unsigned rnd = 0;

  if (tl < NSUP) ysS[epw][tl] = ys[b * NSUP + tl];
  if (tl < NN)   nrmS[epw][tl] = Gq[tl * NN + tl];
  for (int e = tl; e < WAYS * NN; e += 256) {
    int w = e / NN, n = e % NN;
    betaS[epw][w][n] = (n >= w * 5 && n < w * 5 + 5) ? 0.2f : 0.0f;
  }
  __syncthreads();

  auto sinkhorn = [&](int base, int n, float cval, bool clamp) {
    const bool own = (wvl == 0);
    const int r0 = ln, r1 = ln + 64;
    const bool h1 = (r1 < n);
    float p0[WAYS], p1[WAYS];
    float up0 = 0.f, up1 = 0.f, u0 = 0.f, u1 = 0.f;
    int aflag = 0;
    int m = 0; int ysq = -1;
    if (own) {
      #pragma unroll
      for (int w = 0; w < WAYS; ++w) {
        p0[w] = Z[epw][(base + r0) * WAYS + w];
        p1[w] = h1 ? Z[epw][(base + r1) * WAYS + w] : 0.f;
      }
      if (clamp && r0 < NSUP) ysq = ysS[epw][r0];
      u0 = p0[0] + p0[1] + p0[2] + p0[3] + p0[4];
      if (h1) u1 = p1[0] + p1[1] + p1[2] + p1[3] + p1[4];
      float dl = fabsf(up0 - u0);
      if (h1) dl = fmaxf(dl, fabsf(up1 - u1));
      aflag = __any(dl > 1e-3f);
    }
    unsigned target = 0;
    for (;;) {
      if (own) {
        while (m < 1000 && ((unsigned)m < target || aflag)) {
          float i0 = frcpf(u0);
          #pragma unroll
          for (int w = 0; w < WAYS; ++w) p0[w] *= i0;
          up0 = u0;
          if (h1) {
            float i1 = frcpf(u1);
            #pragma unroll
            for (int w = 0; w < WAYS; ++w) p1[w] *= i1;
            up1 = u1;
          }
          #pragma unroll
          for (int w = 0; w < WAYS; ++w) {
            float s = wsum64f_fast(p0[w] + (h1 ? p1[w] : 0.f));
            float f = cval * frcpf(s);
            p0[w] *= f;
            if (h1) p1[w] *= f;
          }
          if (clamp && r0 < NSUP) {
            #pragma unroll
            for (int w = 0; w < WAYS; ++w) p0[w] = (ysq == w) ? 1.f : 0.f;
          }
          ++m;
          u0 = p0[0] + p0[1] + p0[2] + p0[3] + p0[4];
          if (h1) u1 = p1[0] + p1[1] + p1[2] + p1[3] + p1[4];
          if ((unsigned)m >= target) {
            float dl = fabsf(up0 - u0);
            if (h1) dl = fmaxf(dl, fabsf(up1 - u1));
            aflag = __any(dl > 1e-3f);
          } else {
            aflag = 1;
          }
        }
        if (ln == 0) mS[epw] = (unsigned)m;
      }
      __syncthreads();
      if (t == 0) {
        unsigned lm = mS[0] > mS[1] ? mS[0] : mS[1];
        Tsh = grid_barrier_max(ctrlu, blk, rnd, lm);
      }
      __syncthreads();
      ++rnd;
      unsigned T = Tsh;
      if (T == target) break;
      target = T;
    }
    if (own) {
      #pragma unroll
      for (int w = 0; w < WAYS; ++w) {
        Z[epw][(base + r0) * WAYS + w] = p0[w];
        if (h1) Z[epw][(base + r1) * WAYS + w] = p1[w];
      }
    }
    __syncthreads();
  };

  for (int epi = 0; epi <= NEPOCH; ++epi) {
    // gv[w][r] = sum_k G[r][k]*beta[w][k]  (k split over 4 waves per half)
    {
      float a0[WAYS], a1[WAYS];
      #pragma unroll
      for (int w = 0; w < WAYS; ++w) { a0[w] = 0.f; a1[w] = 0.f; }
      int k0 = wvl * 25;
      for (int kk = 0; kk < 25; ++kk) {
        int k = k0 + kk;
        float g0 = Gq[(size_t)k * NN + ln];
        float g1 = (ln < NN - 64) ? Gq[(size_t)k * NN + 64 + ln] : 0.f;
        #pragma unroll
        for (int w = 0; w < WAYS; ++w) {
          float bw = betaS[epw][w][k];
          a0[w] = fmaf(g0, bw, a0[w]);
          a1[w] = fmaf(g1, bw, a1[w]);
        }
      }
      #pragma unroll
      for (int w = 0; w < WAYS; ++w) {
        pbuf[epw][wvl][w * NN + ln] = a0[w];
        if (ln < NN - 64) pbuf[epw][wvl][w * NN + 64 + ln] = a1[w];
      }
    }
    __syncthreads();
    for (int e = tl; e < WAYS * NN; e += 256)
      gvF[epw][e] = ((pbuf[epw][0][e] + pbuf[epw][1][e]) + pbuf[epw][2][e]) + pbuf[epw][3][e];
    __syncthreads();
    if (tl < WAYS) {
      float s = 0.f;
      for (int n = 0; n < NN; ++n) s = fmaf(betaS[epw][tl][n], gvF[epw][tl * NN + n], s);
      pnS[epw][tl] = s;
    }
    __syncthreads();
    for (int e = tl; e < NQ * WAYS; e += 256) {
      int r = NSUP + e / WAYS, w = e % WAYS;
      float d = (nrmS[epw][r] + pnS[epw][w]) - 2.0f * gvF[epw][w * NN + r];
      Z[epw][r * WAYS + w] = expf(-10.0f * (d > 0.f ? d : 0.f));
    }
    __syncthreads();
    sinkhorn(NSUP, NQ, 15.0f, false);

    if (epi == NEPOCH) {
      if (tl == 0) redi[epw] = 0;
      __syncthreads();
      if (tl < NQ) {
        int row = NSUP + tl;
        float bv = Z[epw][row * WAYS + 0]; int am = 0;
        #pragma unroll
        for (int w = 1; w < WAYS; ++w) {
          float v = Z[epw][row * WAYS + w];
          if (v > bv) { bv = v; am = w; }
        }
        if (am == yq[b * NQ + tl]) atomicAdd(&redi[epw], 1);
      }
      __syncthreads();
      if (tl == 0) out[b] = (float)redi[epw] / 75.0f;
    } else {
      if (tl < NSUP) {
        #pragma unroll
        for (int w = 0; w < WAYS; ++w) Z[epw][tl * WAYS + w] = (ysS[epw][tl] == w) ? 1.f : 0.f;
      }
      __syncthreads();
      for (int r = wvl; r < NN; r += 4) {
        float a0 = 0, a1 = 0, a2 = 0, a3 = 0, a4 = 0;
        for (int k = ln; k < NN; k += 64) {
          float iv = Invq[(size_t)r * NN + k];
          a0 = fmaf(iv, Z[epw][k * WAYS + 0], a0);
          a1 = fmaf(iv, Z[epw][k * WAYS + 1], a1);
          a2 = fmaf(iv, Z[epw][k * WAYS + 2], a2);
          a3 = fmaf(iv, Z[epw][k * WAYS + 3], a3);
          a4 = fmaf(iv, Z[epw][k * WAYS + 4], a4);
        }
        a0 = wsum64f_fast(a0); a1 = wsum64f_fast(a1); a2 = wsum64f_fast(a2);
        a3 = wsum64f_fast(a3); a4 = wsum64f_fast(a4);
        if (ln == 0) {
          pbuf[epw][0][r * WAYS + 0] = a0; pbuf[epw][0][r * WAYS + 1] = a1;
          pbuf[epw][0][r * WAYS + 2] = a2; pbuf[epw][0][r * WAYS + 3] = a3;
          pbuf[epw][0][r * WAYS + 4] = a4;
        }
      }
      __syncthreads();
      for (int e = tl; e < NN * WAYS; e += 256) Z[epw][e] = pbuf[epw][0][e];
      __syncthreads();
      sinkhorn(0, NN, 20.0f, true);
      if (tl < WAYS) {
        float s = 0.f;
        for (int r = 0; r < NN; ++r) s += Z[epw][r * WAYS + tl];
        csv[epw][tl] = s;
      }
      __syncthreads();
      for (int e = tl; e < NN * WAYS; e += 256) {
        int n = e / WAYS, w = e % WAYS;
        float nb = Z[epw][n * WAYS + w] / csv[epw][w];
        betaS[epw][w][n] = 0.4f * betaS[epw][w][n] + 0.6f * nb;
      }
      __syncthreads();
    }
  }
}

extern "C" void kernel_launch(void* const* d_in, const int* in_sizes, int n_in,
                              void* d_out, int out_size, void* d_ws, size_t ws_size,
                              hipStream_t stream) {
  const float* xs = (const float*)d_in[0];
  const float* xq = (const float*)d_in[1];
  const int*   ys = (const int*)d_in[2];
  const int*   yq = (const int*)d_in[3];
  float* out = (float*)d_out;
  char* ws   = (char*)d_ws;

  hipMemsetAsync(d_ws, 0, CTRL_BYTES, stream);

  (void)hipFuncSetAttribute((const void*)k1_lds,
                            hipFuncAttributeMaxDynamicSharedMemorySize,
                            DYN_LDS_BYTES);
  hipLaunchKernelGGL(k1_lds, dim3(B_RUNS), dim3(512), DYN_LDS_BYTES, stream, xs, xq, ws);
  hipLaunchKernelGGL(k2_epochs, dim3(KB2), dim3(512), 0, stream, ys, yq, ws, out);
}